// Round 1
// baseline (12547.938 us; speedup 1.0000x reference)
//
#include <hip/hip_runtime.h>
#include <math.h>

#define B 8
#define S 128
#define D 512
#define M 4
#define BS 1024
#define BSD 524288          // B*S*D
#define DEPTH 16
#define THRESH 0.9999f
#define EPS 1e-6f
#define SCALE 0.04419417382415922f   // D^-0.5

// ---------------- workspace layout (float offsets) ----------------
#define OFF_ZR   0
#define OFF_ZI   (1*BSD)
#define OFF_AR   (2*BSD)
#define OFF_AI   (3*BSD)
#define OFF_QR   (4*BSD)    // each of q/k/v r/i is M*BSD = 4*BSD
#define OFF_QI   (8*BSD)
#define OFF_KR   (12*BSD)
#define OFF_KI   (16*BSD)
#define OFF_VR   (20*BSD)
#define OFF_VI   (24*BSD)
#define OFF_OR   (28*BSD)
#define OFF_OI   (32*BSD)
#define OFF_ATTN (36*BSD)   // M*B*S*S = 524288
#define OFF_FEAT (37*BSD)            // M*B*2D = 65536
#define OFF_GWP  (37*BSD + 65536)    // B*2D = 8192
#define OFF_H0   (37*BSD + 73728)    // B*D = 4096
#define OFF_H1   (37*BSD + 77824)
#define OFF_CUM  (37*BSD + 81920)    // 8
#define OFF_W    (37*BSD + 81928)    // M*B = 32, layout [m][b]
#define OFF_WT   (37*BSD + 81960)    // 8
// total ~ (37*BSD + 81968)*4 bytes ~ 78 MB

// ---------------- init: carry state ----------------
__global__ __launch_bounds__(256) void k_init(const float* __restrict__ xr,
                                              const float* __restrict__ xi,
                                              float* __restrict__ ws) {
  int i4 = blockIdx.x * 256 + threadIdx.x;      // BSD/4 = 131072 float4s
  float4 a = ((const float4*)xr)[i4];
  float4 b = ((const float4*)xi)[i4];
  ((float4*)(ws + OFF_ZR))[i4] = a;
  ((float4*)(ws + OFF_ZI))[i4] = b;
  float4 z = {0.f, 0.f, 0.f, 0.f};
  ((float4*)(ws + OFF_AR))[i4] = z;
  ((float4*)(ws + OFF_AI))[i4] = z;
  if (i4 < (B * D) / 4) {
    ((float4*)(ws + OFF_H0))[i4] = z;
    ((float4*)(ws + OFF_H1))[i4] = z;
  }
  if (i4 < B) ws[OFF_CUM + i4] = 0.f;
}

// ---------------- gwp / pooled: mean over S of zr|zi -> [B,2D] ----------------
__global__ __launch_bounds__(256) void k_gwp(const float* __restrict__ zr,
                                             const float* __restrict__ zi,
                                             float* __restrict__ gwp) {
  int idx = blockIdx.x * 256 + threadIdx.x;     // B*2D = 8192
  int b = idx >> 10;
  int f = idx & 1023;
  const float* src = (f < D) ? (zr + b * S * D + f) : (zi + b * S * D + (f - D));
  float s = 0.f;
#pragma unroll 8
  for (int ss = 0; ss < S; ++ss) s += src[ss * D];
  gwp[idx] = s * (1.0f / S);
}

// ---------------- GRU gates (grid (4, B), 128 thr): h_new ----------------
__global__ __launch_bounds__(128) void k_gru(const float* __restrict__ gwp,
                                             const float* __restrict__ hold,
                                             float* __restrict__ hnew,
                                             const float* __restrict__ Wih,
                                             const float* __restrict__ Whh,
                                             const float* __restrict__ bih,
                                             const float* __restrict__ bhh) {
  __shared__ float pl[2 * D];
  __shared__ float hb[D];
  int b = blockIdx.y;
  int t = threadIdx.x;
  for (int f = t; f < 2 * D; f += 128) pl[f] = gwp[b * 2 * D + f];
  for (int d2 = t; d2 < D; d2 += 128) hb[d2] = hold[b * D + d2];
  __syncthreads();
  int dd = blockIdx.x * 128 + t;                 // 0..511
  float xr_ = bih[dd], xz_ = bih[D + dd], xn_ = bih[2 * D + dd];
#pragma unroll 4
  for (int f = 0; f < 2 * D; ++f) {
    float p = pl[f];
    const float* row = Wih + f * 3 * D;
    xr_ += p * row[dd];
    xz_ += p * row[D + dd];
    xn_ += p * row[2 * D + dd];
  }
  float hr_ = bhh[dd], hz_ = bhh[D + dd], hn_ = bhh[2 * D + dd];
#pragma unroll 4
  for (int d2 = 0; d2 < D; ++d2) {
    float hh = hb[d2];
    const float* row = Whh + d2 * 3 * D;
    hr_ += hh * row[dd];
    hz_ += hh * row[D + dd];
    hn_ += hh * row[2 * D + dd];
  }
  float r = 1.f / (1.f + expf(-(xr_ + hr_)));
  float z = 1.f / (1.f + expf(-(xz_ + hz_)));
  float n = tanhf(xn_ + r * hn_);
  hnew[b * D + dd] = (1.f - z) * n + z * hb[dd];
}

// ---------------- QKV complex projections (the big GEMM) ----------------
// grid (D/64, BS/64, M*6), 256 thr. out = Xr@Wa + sgn * Xi@Wb
__global__ __launch_bounds__(256) void k_qkv(float* __restrict__ ws,
                                             const float* __restrict__ Wqr,
                                             const float* __restrict__ Wqi,
                                             const float* __restrict__ Wkr,
                                             const float* __restrict__ Wki,
                                             const float* __restrict__ Wvr,
                                             const float* __restrict__ Wvi) {
  __shared__ float As[16][68], As2[16][68];
  __shared__ float Bs[16][64], Bs2[16][64];
  int m = blockIdx.z / 6, w6 = blockIdx.z % 6;
  const float *Wa, *Wb;
  float sgn;
  int off;
  switch (w6) {
    case 0:  Wa = Wqr; Wb = Wqi; sgn = -1.f; off = OFF_QR; break;
    case 1:  Wa = Wqi; Wb = Wqr; sgn =  1.f; off = OFF_QI; break;
    case 2:  Wa = Wkr; Wb = Wki; sgn = -1.f; off = OFF_KR; break;
    case 3:  Wa = Wki; Wb = Wkr; sgn =  1.f; off = OFF_KI; break;
    case 4:  Wa = Wvr; Wb = Wvi; sgn = -1.f; off = OFF_VR; break;
    default: Wa = Wvi; Wb = Wvr; sgn =  1.f; off = OFF_VI; break;
  }
  Wa += m * D * D;
  Wb += m * D * D;
  float* out = ws + off + m * BSD;
  const float* Xr = ws + OFF_ZR;
  const float* Xi = ws + OFF_ZI;
  int row0 = blockIdx.y * 64, col0 = blockIdx.x * 64;
  int t = threadIdx.x, ty = t >> 4, tx = t & 15;
  int lr = t >> 2, lk = (t & 3) * 4;             // A loader: 64 rows x 4 float4
  int bk = t >> 4, bc = (t & 15) * 4;            // B loader: 16 k x 16 float4
  float acc[4][4] = {};
  for (int k0 = 0; k0 < D; k0 += 16) {
    float4 a = *(const float4*)(Xr + (row0 + lr) * D + k0 + lk);
    As[lk][lr] = a.x; As[lk + 1][lr] = a.y; As[lk + 2][lr] = a.z; As[lk + 3][lr] = a.w;
    a = *(const float4*)(Xi + (row0 + lr) * D + k0 + lk);
    As2[lk][lr] = a.x; As2[lk + 1][lr] = a.y; As2[lk + 2][lr] = a.z; As2[lk + 3][lr] = a.w;
    float4 bv = *(const float4*)(Wa + (k0 + bk) * D + col0 + bc);
    *(float4*)&Bs[bk][bc] = bv;
    bv = *(const float4*)(Wb + (k0 + bk) * D + col0 + bc);
    bv.x *= sgn; bv.y *= sgn; bv.z *= sgn; bv.w *= sgn;
    *(float4*)&Bs2[bk][bc] = bv;
    __syncthreads();
#pragma unroll
    for (int kk = 0; kk < 16; ++kk) {
      float4 a1 = *(const float4*)&As[kk][ty * 4];
      float4 a2 = *(const float4*)&As2[kk][ty * 4];
      float4 b1 = *(const float4*)&Bs[kk][tx * 4];
      float4 b2 = *(const float4*)&Bs2[kk][tx * 4];
      float av1[4] = {a1.x, a1.y, a1.z, a1.w}, av2[4] = {a2.x, a2.y, a2.z, a2.w};
      float bv1[4] = {b1.x, b1.y, b1.z, b1.w}, bv2[4] = {b2.x, b2.y, b2.z, b2.w};
#pragma unroll
      for (int i = 0; i < 4; ++i)
#pragma unroll
        for (int j = 0; j < 4; ++j)
          acc[i][j] += av1[i] * bv1[j] + av2[i] * bv2[j];
    }
    __syncthreads();
  }
#pragma unroll
  for (int i = 0; i < 4; ++i) {
    float4 o = {acc[i][0], acc[i][1], acc[i][2], acc[i][3]};
    *(float4*)(out + (row0 + ty * 4 + i) * D + col0 + tx * 4) = o;
  }
}

// ---------------- scores + row softmax: attn[m,b,s,t] ----------------
// grid (S/32, M*B), 256 thr. scores = (qr.kr + qi.ki)*SCALE, softmax over t.
__global__ __launch_bounds__(256) void k_attn(float* __restrict__ ws) {
  __shared__ float Qr[16][36], Qi[16][36], Kr[16][132], Ki[16][132];
  int stile = blockIdx.x, mb = blockIdx.y;
  int t = threadIdx.x, ty = t >> 5, tx = t & 31;
  const float* qr = ws + OFF_QR + (mb * S + stile * 32) * D;
  const float* qi = ws + OFF_QI + (mb * S + stile * 32) * D;
  const float* kr = ws + OFF_KR + mb * S * D;
  const float* ki = ws + OFF_KI + mb * S * D;
  float acc[4][4] = {};
  int qrow = t >> 3, qk = (t & 7) * 2;
  int krow = t >> 2, kk4 = (t & 3) * 4;
  for (int k0 = 0; k0 < D; k0 += 16) {
    float2 q2 = *(const float2*)(qr + qrow * D + k0 + qk);
    Qr[qk][qrow] = q2.x; Qr[qk + 1][qrow] = q2.y;
    q2 = *(const float2*)(qi + qrow * D + k0 + qk);
    Qi[qk][qrow] = q2.x; Qi[qk + 1][qrow] = q2.y;
#pragma unroll
    for (int rr = 0; rr < 2; ++rr) {
      int row = krow + rr * 64;
      float4 k4 = *(const float4*)(kr + row * D + k0 + kk4);
      Kr[kk4][row] = k4.x; Kr[kk4 + 1][row] = k4.y; Kr[kk4 + 2][row] = k4.z; Kr[kk4 + 3][row] = k4.w;
      k4 = *(const float4*)(ki + row * D + k0 + kk4);
      Ki[kk4][row] = k4.x; Ki[kk4 + 1][row] = k4.y; Ki[kk4 + 2][row] = k4.z; Ki[kk4 + 3][row] = k4.w;
    }
    __syncthreads();
#pragma unroll
    for (int kk = 0; kk < 16; ++kk) {
      float4 a1 = *(const float4*)&Qr[kk][ty * 4];
      float4 a2 = *(const float4*)&Qi[kk][ty * 4];
      float4 b1 = *(const float4*)&Kr[kk][tx * 4];
      float4 b2 = *(const float4*)&Ki[kk][tx * 4];
      float av1[4] = {a1.x, a1.y, a1.z, a1.w}, av2[4] = {a2.x, a2.y, a2.z, a2.w};
      float bv1[4] = {b1.x, b1.y, b1.z, b1.w}, bv2[4] = {b2.x, b2.y, b2.z, b2.w};
#pragma unroll
      for (int i = 0; i < 4; ++i)
#pragma unroll
        for (int j = 0; j < 4; ++j)
          acc[i][j] += av1[i] * bv1[j] + av2[i] * bv2[j];
    }
    __syncthreads();
  }
  float* attn = ws + OFF_ATTN + mb * S * S;
#pragma unroll
  for (int i = 0; i < 4; ++i) {
    int srow = stile * 32 + ty * 4 + i;
    float v[4];
    float mx = -1e30f;
#pragma unroll
    for (int j = 0; j < 4; ++j) { v[j] = acc[i][j] * SCALE; mx = fmaxf(mx, v[j]); }
    for (int o = 1; o < 32; o <<= 1) mx = fmaxf(mx, __shfl_xor(mx, o));
    float sm = 0.f;
#pragma unroll
    for (int j = 0; j < 4; ++j) { v[j] = __expf(v[j] - mx); sm += v[j]; }
    for (int o = 1; o < 32; o <<= 1) sm += __shfl_xor(sm, o);
    float inv = 1.f / sm;
    float4 o4 = {v[0] * inv, v[1] * inv, v[2] * inv, v[3] * inv};
    *(float4*)(attn + srow * S + tx * 4) = o4;
  }
}

// ---------------- PV: o{r,i}[m,b,s,e] = attn @ v{r,i} ----------------
// grid (D/64, S/32, M*B), 256 thr
__global__ __launch_bounds__(256) void k_pv(float* __restrict__ ws) {
  __shared__ float Ps[16][36], Vr[16][64], Vi[16][64];
  int ex = blockIdx.x * 64, sy = blockIdx.y * 32, mb = blockIdx.z;
  int t = threadIdx.x, ty = t >> 5, tx = t & 31;
  const float* attn = ws + OFF_ATTN + (mb * S + sy) * S;
  const float* vr = ws + OFF_VR + mb * S * D + ex;
  const float* vi = ws + OFF_VI + mb * S * D + ex;
  float ar_[4][2] = {}, ai_[4][2] = {};
  int prow = t >> 3, pk = (t & 7) * 2;
  int vk = t >> 4, ve = (t & 15) * 4;
  for (int k0 = 0; k0 < S; k0 += 16) {
    float2 p2 = *(const float2*)(attn + prow * S + k0 + pk);
    Ps[pk][prow] = p2.x; Ps[pk + 1][prow] = p2.y;
    float4 v4 = *(const float4*)(vr + (k0 + vk) * D + ve);
    *(float4*)&Vr[vk][ve] = v4;
    v4 = *(const float4*)(vi + (k0 + vk) * D + ve);
    *(float4*)&Vi[vk][ve] = v4;
    __syncthreads();
#pragma unroll
    for (int kk = 0; kk < 16; ++kk) {
      float4 a = *(const float4*)&Ps[kk][ty * 4];
      float2 br = *(const float2*)&Vr[kk][tx * 2];
      float2 bi = *(const float2*)&Vi[kk][tx * 2];
      float av[4] = {a.x, a.y, a.z, a.w};
#pragma unroll
      for (int i = 0; i < 4; ++i) {
        ar_[i][0] += av[i] * br.x; ar_[i][1] += av[i] * br.y;
        ai_[i][0] += av[i] * bi.x; ai_[i][1] += av[i] * bi.y;
      }
    }
    __syncthreads();
  }
  float* orp = ws + OFF_OR + (mb * S + sy) * D + ex;
  float* oip = ws + OFF_OI + (mb * S + sy) * D + ex;
#pragma unroll
  for (int i = 0; i < 4; ++i) {
    float2 o1 = {ar_[i][0], ar_[i][1]};
    float2 o2 = {ai_[i][0], ai_[i][1]};
    *(float2*)(orp + (ty * 4 + i) * D + tx * 2) = o1;
    *(float2*)(oip + (ty * 4 + i) * D + tx * 2) = o2;
  }
}

// ---------------- ModReLU + ComplexLayerNorm (in place on OR/OI) ----------------
// grid M*B*S blocks, 64 thr (one wave) per (m,b,s) row of D
__global__ __launch_bounds__(64) void k_modln(float* __restrict__ ws,
                                              const float* __restrict__ mod_bias,
                                              const float* __restrict__ ln_scale,
                                              const float* __restrict__ ln_shift) {
  int blk = blockIdx.x;
  int m = blk / (B * S);
  int t = threadIdx.x;
  float* orp = ws + OFF_OR + (size_t)blk * D;
  float* oip = ws + OFF_OI + (size_t)blk * D;
  float orv[2][4], oiv[2][4], magv[2][4];
  float sum = 0.f, sumsq = 0.f;
#pragma unroll
  for (int k = 0; k < 2; ++k) {
    float4 a = *(const float4*)(orp + t * 4 + k * 256);
    float4 c = *(const float4*)(oip + t * 4 + k * 256);
    float av[4] = {a.x, a.y, a.z, a.w}, cv[4] = {c.x, c.y, c.z, c.w};
#pragma unroll
    for (int j = 0; j < 4; ++j) {
      int e = t * 4 + k * 256 + j;
      float o_r = av[j], o_i = cv[j];
      float mag = sqrtf(o_r * o_r + o_i * o_i) + EPS;
      float g = fmaxf(mag + mod_bias[m * D + e], 0.f) / mag;
      o_r *= g; o_i *= g;
      orv[k][j] = o_r; oiv[k][j] = o_i;
      float mag2 = sqrtf(o_r * o_r + o_i * o_i) + EPS;
      magv[k][j] = mag2;
      sum += mag2;
      sumsq += mag2 * mag2;
    }
  }
  for (int o = 1; o < 64; o <<= 1) {
    sum += __shfl_xor(sum, o);
    sumsq += __shfl_xor(sumsq, o);
  }
  float mu = sum * (1.f / D);
  float var = (sumsq - (float)D * mu * mu) * (1.f / (D - 1));
  float inv = 1.f / sqrtf(var + EPS);
#pragma unroll
  for (int k = 0; k < 2; ++k) {
#pragma unroll
    for (int j = 0; j < 4; ++j) {
      int e = t * 4 + k * 256 + j;
      float nm = (magv[k][j] - mu) * inv * ln_scale[m * D + e] + ln_shift[m * D + e];
      float hyp = magv[k][j] - EPS;   // = |o| post-modrelu
      float cp, sp;
      if (hyp > 0.f) { cp = orv[k][j] / hyp; sp = oiv[k][j] / hyp; }
      else           { cp = 1.f;             sp = 0.f; }
      orv[k][j] = nm * cp;
      oiv[k][j] = nm * sp;
    }
    float4 a = {orv[k][0], orv[k][1], orv[k][2], orv[k][3]};
    float4 c = {oiv[k][0], oiv[k][1], oiv[k][2], oiv[k][3]};
    *(float4*)(orp + t * 4 + k * 256) = a;
    *(float4*)(oip + t * 4 + k * 256) = c;
  }
}

// ---------------- feat[m,b,f] = mean over s of mr|mi ----------------
__global__ __launch_bounds__(256) void k_feat(float* __restrict__ ws) {
  int idx = blockIdx.x * 256 + threadIdx.x;   // M*B*2D = 65536
  int mb = idx >> 10;
  int f = idx & 1023;
  const float* src = ws + ((f < D) ? OFF_OR : OFF_OI) + mb * S * D + ((f < D) ? f : f - D);
  float s = 0.f;
#pragma unroll 8
  for (int ss = 0; ss < S; ++ss) s += src[ss * D];
  ws[OFF_FEAT + idx] = s * (1.0f / S);
}

// ---------------- mbias + salience + module softmax -> w[m,b] ----------------
__global__ __launch_bounds__(256) void k_wsel(float* __restrict__ ws,
                                              const float* __restrict__ hnew,
                                              const float* __restrict__ bias_W,
                                              const float* __restrict__ bias_b,
                                              const float* __restrict__ w_sal) {
  __shared__ float mb_s[B][M];
  __shared__ float sal_s[M][B];
  int t = threadIdx.x;
  int p = t >> 3, l = t & 7;
  {
    int b = p >> 2, m = p & 3;
    float s = 0.f;
    for (int d2 = l; d2 < D; d2 += 8) s += hnew[b * D + d2] * bias_W[d2 * M + m];
    for (int o = 1; o < 8; o <<= 1) s += __shfl_xor(s, o);
    if (l == 0) mb_s[b][m] = s + bias_b[m];
  }
  {
    int m = p >> 3, b = p & 7;
    float s = 0.f;
    for (int f = l; f < 2 * D; f += 8) s += ws[OFF_FEAT + (m * B + b) * 2 * D + f] * w_sal[m * 2 * D + f];
    for (int o = 1; o < 8; o <<= 1) s += __shfl_xor(s, o);
    if (l == 0) sal_s[m][b] = s;
  }
  __syncthreads();
  if (t < B) {
    int b = t;
    float lg[M], mx = -1e30f;
#pragma unroll
    for (int m = 0; m < M; ++m) { lg[m] = sal_s[m][b] + mb_s[b][m]; mx = fmaxf(mx, lg[m]); }
    float sm = 0.f;
#pragma unroll
    for (int m = 0; m < M; ++m) { lg[m] = expf(lg[m] - mx); sm += lg[m]; }
    float inv = 1.f / sm;
#pragma unroll
    for (int m = 0; m < M; ++m) ws[OFF_W + m * B + b] = lg[m] * inv;
  }
}

// ---------------- workspace broadcast: z{r,i} <- sum_m w[m,b]*m{r,i} ----------------
__global__ __launch_bounds__(256) void k_bcast(float* __restrict__ ws) {
  int i4 = blockIdx.x * 256 + threadIdx.x;    // BSD/4
  int b = i4 >> 14;                           // (S*D)/4 = 16384
  float w0 = ws[OFF_W + 0 * B + b], w1 = ws[OFF_W + 1 * B + b];
  float w2 = ws[OFF_W + 2 * B + b], w3 = ws[OFF_W + 3 * B + b];
  const float4* mr = (const float4*)(ws + OFF_OR);
  const float4* mi = (const float4*)(ws + OFF_OI);
  const int MS = BSD / 4;
  float4 r0 = mr[i4], r1 = mr[i4 + MS], r2 = mr[i4 + 2 * MS], r3 = mr[i4 + 3 * MS];
  float4 g;
  g.x = w0 * r0.x + w1 * r1.x + w2 * r2.x + w3 * r3.x;
  g.y = w0 * r0.y + w1 * r1.y + w2 * r2.y + w3 * r3.y;
  g.z = w0 * r0.z + w1 * r1.z + w2 * r2.z + w3 * r3.z;
  g.w = w0 * r0.w + w1 * r1.w + w2 * r2.w + w3 * r3.w;
  ((float4*)(ws + OFF_ZR))[i4] = g;
  float4 s0 = mi[i4], s1 = mi[i4 + MS], s2 = mi[i4 + 2 * MS], s3 = mi[i4 + 3 * MS];
  g.x = w0 * s0.x + w1 * s1.x + w2 * s2.x + w3 * s3.x;
  g.y = w0 * s0.y + w1 * s1.y + w2 * s2.y + w3 * s3.y;
  g.z = w0 * s0.z + w1 * s1.z + w2 * s2.z + w3 * s3.z;
  g.w = w0 * s0.w + w1 * s1.w + w2 * s2.w + w3 * s3.w;
  ((float4*)(ws + OFF_ZI))[i4] = g;
}

// ---------------- halting: p, wt, cum ----------------
__global__ __launch_bounds__(256) void k_halt(float* __restrict__ ws,
                                              const float* __restrict__ w_halt,
                                              const float* __restrict__ b_halt) {
  int t = threadIdx.x;
  int b = t >> 5, l = t & 31;
  float s = 0.f;
  for (int f = l; f < 2 * D; f += 32) s += ws[OFF_GWP + b * 2 * D + f] * w_halt[f];
  for (int o = 1; o < 32; o <<= 1) s += __shfl_xor(s, o);
  if (l == 0) {
    float p = 1.f / (1.f + expf(-(s + b_halt[0])));
    float cum = ws[OFF_CUM + b];
    float still = (cum < THRESH) ? 1.f : 0.f;
    bool nh = ((cum + p) >= THRESH) && (cum < THRESH);
    float wt = (nh ? (1.f - cum) : p) * still;
    ws[OFF_CUM + b] = cum + wt;
    ws[OFF_WT + b] = wt;
  }
}

// ---------------- ACT accumulate: a{r,i} += wt[b]*z{r,i} ----------------
__global__ __launch_bounds__(256) void k_acc(float* __restrict__ ws) {
  int i4 = blockIdx.x * 256 + threadIdx.x;
  int b = i4 >> 14;
  float wt = ws[OFF_WT + b];
  float4 z = ((const float4*)(ws + OFF_ZR))[i4];
  float4 a = ((float4*)(ws + OFF_AR))[i4];
  a.x += wt * z.x; a.y += wt * z.y; a.z += wt * z.z; a.w += wt * z.w;
  ((float4*)(ws + OFF_AR))[i4] = a;
  z = ((const float4*)(ws + OFF_ZI))[i4];
  a = ((float4*)(ws + OFF_AI))[i4];
  a.x += wt * z.x; a.y += wt * z.y; a.z += wt * z.z; a.w += wt * z.w;
  ((float4*)(ws + OFF_AI))[i4] = a;
}

// ---------------- output: stack([ar, ai]) ----------------
__global__ __launch_bounds__(256) void k_out(const float* __restrict__ ws,
                                             float* __restrict__ out) {
  int i4 = blockIdx.x * 256 + threadIdx.x;
  ((float4*)out)[i4] = ((const float4*)(ws + OFF_AR))[i4];
  ((float4*)out)[i4 + BSD / 4] = ((const float4*)(ws + OFF_AI))[i4];
}

extern "C" void kernel_launch(void* const* d_in, const int* in_sizes, int n_in,
                              void* d_out, int out_size, void* d_ws, size_t ws_size,
                              hipStream_t stream) {
  (void)in_sizes; (void)n_in; (void)out_size; (void)ws_size;
  const float* x_real  = (const float*)d_in[0];
  const float* x_imag  = (const float*)d_in[1];
  const float* Wq_r    = (const float*)d_in[2];
  const float* Wq_i    = (const float*)d_in[3];
  const float* Wk_r    = (const float*)d_in[4];
  const float* Wk_i    = (const float*)d_in[5];
  const float* Wv_r    = (const float*)d_in[6];
  const float* Wv_i    = (const float*)d_in[7];
  const float* mod_bias = (const float*)d_in[8];
  const float* ln_scale = (const float*)d_in[9];
  const float* ln_shift = (const float*)d_in[10];
  const float* w_sal   = (const float*)d_in[11];
  const float* gru_Wih = (const float*)d_in[12];
  const float* gru_Whh = (const float*)d_in[13];
  const float* gru_bih = (const float*)d_in[14];
  const float* gru_bhh = (const float*)d_in[15];
  const float* bias_W  = (const float*)d_in[16];
  const float* bias_b  = (const float*)d_in[17];
  const float* w_halt  = (const float*)d_in[18];
  const float* b_halt  = (const float*)d_in[19];
  float* ws = (float*)d_ws;
  float* out = (float*)d_out;

  k_init<<<512, 256, 0, stream>>>(x_real, x_imag, ws);
  k_gwp<<<32, 256, 0, stream>>>(ws + OFF_ZR, ws + OFF_ZI, ws + OFF_GWP);
  for (int step = 0; step < DEPTH; ++step) {
    const float* hold = ws + ((step & 1) ? OFF_H1 : OFF_H0);
    float* hnew = ws + ((step & 1) ? OFF_H0 : OFF_H1);
    k_gru<<<dim3(4, 8), 128, 0, stream>>>(ws + OFF_GWP, hold, hnew,
                                          gru_Wih, gru_Whh, gru_bih, gru_bhh);
    k_qkv<<<dim3(8, 16, 24), 256, 0, stream>>>(ws, Wq_r, Wq_i, Wk_r, Wk_i, Wv_r, Wv_i);
    k_attn<<<dim3(4, 32), 256, 0, stream>>>(ws);
    k_pv<<<dim3(8, 4, 32), 256, 0, stream>>>(ws);
    k_modln<<<M * B * S, 64, 0, stream>>>(ws, mod_bias, ln_scale, ln_shift);
    k_feat<<<256, 256, 0, stream>>>(ws);
    k_wsel<<<1, 256, 0, stream>>>(ws, hnew, bias_W, bias_b, w_sal);
    k_bcast<<<512, 256, 0, stream>>>(ws);
    k_gwp<<<32, 256, 0, stream>>>(ws + OFF_ZR, ws + OFF_ZI, ws + OFF_GWP);
    k_halt<<<1, 256, 0, stream>>>(ws, w_halt, b_halt);
    k_acc<<<512, 256, 0, stream>>>(ws);
  }
  k_out<<<512, 256, 0, stream>>>(ws, out);
}

// Round 6
// 6328.840 us; speedup vs baseline: 1.9827x; 1.9827x over previous
//
#include <hip/hip_runtime.h>
#include <math.h>

#define B 8
#define S 128
#define D 512
#define M 4
#define BS 1024
#define BSD 524288          // B*S*D
#define DEPTH 16
#define THRESH 0.9999f
#define EPS 1e-6f
#define SCALE 0.04419417382415922f   // D^-0.5

typedef float floatx4 __attribute__((ext_vector_type(4)));
typedef short s8v __attribute__((ext_vector_type(8)));
typedef unsigned short us4 __attribute__((ext_vector_type(4)));

__device__ __forceinline__ unsigned short f2bf(float f) {
  unsigned int u = __float_as_uint(f);
  u += 0x7FFFu + ((u >> 16) & 1u);          // round-to-nearest-even
  return (unsigned short)(u >> 16);
}
__device__ __forceinline__ float bf2f(unsigned short h) {
  return __uint_as_float((unsigned int)h << 16);
}

// ---------------- workspace layout (float-slot offsets) — R1 base + bf16 annex ----------------
#define OFF_ZR   0
#define OFF_ZI   (1*BSD)
#define OFF_AR   (2*BSD)
#define OFF_AI   (3*BSD)
#define OFF_QR   (4*BSD)    // each of q/k/v r/i fp32: M*BSD = 4*BSD
#define OFF_QI   (8*BSD)
#define OFF_KR   (12*BSD)
#define OFF_KI   (16*BSD)
#define OFF_VR   (20*BSD)
#define OFF_VI   (24*BSD)
#define OFF_OR   (28*BSD)
#define OFF_OI   (32*BSD)
#define OFF_ATTN (36*BSD)
#define OFF_FEAT (37*BSD)
#define OFF_GWP  (37*BSD + 65536)
#define OFF_H0   (37*BSD + 73728)
#define OFF_H1   (37*BSD + 77824)
#define OFF_CUM  (37*BSD + 81920)
#define OFF_W    (37*BSD + 81928)
#define OFF_WT   (37*BSD + 81960)
// bf16 annex. xcat hi/lo: [1024][1024] bf16 = BSD slots each.
// Weight planes: 24 matrices (m*6+{qr,qi,kr,ki,vr,vi}) of [512 n][512 k] bf16, hi & lo = 6*BSD slots each.
#define OFF_XH   (37*BSD + 90112)
#define OFF_XL   (OFF_XH + 1*BSD)
#define OFF_WH   (OFF_XH + 2*BSD)
#define OFF_WL   (OFF_XH + 8*BSD)
// end = 51*BSD + 90112 slots ~ 107.3 MB (R5 functioned at ~105 MB)

// ---------------- init: fp32 carry + bf16 hi/lo Xcat ----------------
__global__ __launch_bounds__(256) void k_init(const float* __restrict__ xr,
                                              const float* __restrict__ xi,
                                              float* __restrict__ ws) {
  unsigned short* xh = (unsigned short*)(ws + OFF_XH);
  unsigned short* xl = (unsigned short*)(ws + OFF_XL);
  int i4 = blockIdx.x * 256 + threadIdx.x;      // BSD/4
  float4 a = ((const float4*)xr)[i4];
  float4 b = ((const float4*)xi)[i4];
  ((float4*)(ws + OFF_ZR))[i4] = a;
  ((float4*)(ws + OFF_ZI))[i4] = b;
  float4 z = {0.f, 0.f, 0.f, 0.f};
  ((float4*)(ws + OFF_AR))[i4] = z;
  ((float4*)(ws + OFF_AI))[i4] = z;
  int row = i4 >> 7;
  int d4 = (i4 & 127) * 4;
  float av[4] = {a.x, a.y, a.z, a.w}, bv[4] = {b.x, b.y, b.z, b.w};
  us4 hh, hl;
#pragma unroll
  for (int j = 0; j < 4; ++j) {
    unsigned short h = f2bf(av[j]); hh[j] = h; hl[j] = f2bf(av[j] - bf2f(h));
  }
  *(us4*)(xh + (size_t)row * 1024 + d4) = hh;
  *(us4*)(xl + (size_t)row * 1024 + d4) = hl;
#pragma unroll
  for (int j = 0; j < 4; ++j) {
    unsigned short h = f2bf(bv[j]); hh[j] = h; hl[j] = f2bf(bv[j] - bf2f(h));
  }
  *(us4*)(xh + (size_t)row * 1024 + 512 + d4) = hh;
  *(us4*)(xl + (size_t)row * 1024 + 512 + d4) = hl;
  if (i4 < (B * D) / 4) {
    ((float4*)(ws + OFF_H0))[i4] = z;
    ((float4*)(ws + OFF_H1))[i4] = z;
  }
  if (i4 < B) ws[OFF_CUM + i4] = 0.f;
}

// ---------------- weight prep: transpose each W[m] -> [n][k] bf16 hi/lo planes ----------------
// grid (8, 8, 24): 64k x 64n tiles; z = m*6+idx, idx in {qr,qi,kr,ki,vr,vi}
__global__ __launch_bounds__(256) void k_wprep(const float* __restrict__ Wqr,
                                               const float* __restrict__ Wqi,
                                               const float* __restrict__ Wkr,
                                               const float* __restrict__ Wki,
                                               const float* __restrict__ Wvr,
                                               const float* __restrict__ Wvi,
                                               float* __restrict__ ws) {
  __shared__ float lt[64][65];
  unsigned short* wh = (unsigned short*)(ws + OFF_WH);
  unsigned short* wl = (unsigned short*)(ws + OFF_WL);
  int z = blockIdx.z, m = z / 6, idx = z % 6;
  const float* Wsrc;
  switch (idx) {
    case 0:  Wsrc = Wqr; break;
    case 1:  Wsrc = Wqi; break;
    case 2:  Wsrc = Wkr; break;
    case 3:  Wsrc = Wki; break;
    case 4:  Wsrc = Wvr; break;
    default: Wsrc = Wvi; break;
  }
  Wsrc += (size_t)m * D * D;
  int k0 = blockIdx.x * 64, n0 = blockIdx.y * 64;
  int tx = threadIdx.x & 63, ty = threadIdx.x >> 6;
#pragma unroll
  for (int i = 0; i < 16; ++i) {
    int kl = ty + i * 4;
    lt[kl][tx] = Wsrc[(size_t)(k0 + kl) * D + n0 + tx];
  }
  __syncthreads();
  unsigned short* whp = wh + (size_t)z * 262144;
  unsigned short* wlp = wl + (size_t)z * 262144;
#pragma unroll
  for (int i = 0; i < 16; ++i) {
    int nl = ty + i * 4;
    float v = lt[tx][nl];
    unsigned short h = f2bf(v);
    whp[(size_t)(n0 + nl) * 512 + k0 + tx] = h;
    wlp[(size_t)(n0 + nl) * 512 + k0 + tx] = f2bf(v - bf2f(h));
  }
}

// ---------------- gwp (R1) ----------------
__global__ __launch_bounds__(256) void k_gwp(const float* __restrict__ zr,
                                             const float* __restrict__ zi,
                                             float* __restrict__ gwp) {
  int idx = blockIdx.x * 256 + threadIdx.x;
  int b = idx >> 10;
  int f = idx & 1023;
  const float* src = (f < D) ? (zr + b * S * D + f) : (zi + b * S * D + (f - D));
  float s = 0.f;
#pragma unroll 8
  for (int ss = 0; ss < S; ++ss) s += src[ss * D];
  gwp[idx] = s * (1.0f / S);
}

// ---------------- GRU (R1) ----------------
__global__ __launch_bounds__(128) void k_gru(const float* __restrict__ gwp,
                                             const float* __restrict__ hold,
                                             float* __restrict__ hnew,
                                             const float* __restrict__ Wih,
                                             const float* __restrict__ Whh,
                                             const float* __restrict__ bih,
                                             const float* __restrict__ bhh) {
  __shared__ float pl[2 * D];
  __shared__ float hb[D];
  int b = blockIdx.y;
  int t = threadIdx.x;
  for (int f = t; f < 2 * D; f += 128) pl[f] = gwp[b * 2 * D + f];
  for (int d2 = t; d2 < D; d2 += 128) hb[d2] = hold[b * D + d2];
  __syncthreads();
  int dd = blockIdx.x * 128 + t;
  float xr_ = bih[dd], xz_ = bih[D + dd], xn_ = bih[2 * D + dd];
#pragma unroll 4
  for (int f = 0; f < 2 * D; ++f) {
    float p = pl[f];
    const float* row = Wih + f * 3 * D;
    xr_ += p * row[dd];
    xz_ += p * row[D + dd];
    xn_ += p * row[2 * D + dd];
  }
  float hr_ = bhh[dd], hz_ = bhh[D + dd], hn_ = bhh[2 * D + dd];
#pragma unroll 4
  for (int d2 = 0; d2 < D; ++d2) {
    float hh = hb[d2];
    const float* row = Whh + d2 * 3 * D;
    hr_ += hh * row[dd];
    hz_ += hh * row[D + dd];
    hn_ += hh * row[2 * D + dd];
  }
  float r = 1.f / (1.f + expf(-(xr_ + hr_)));
  float z = 1.f / (1.f + expf(-(xz_ + hz_)));
  float n = tanhf(xn_ + r * hn_);
  hnew[b * D + dd] = (1.f - z) * n + z * hb[dd];
}

// ---------------- QKV: bf16x3 split-MFMA GEMM, fp32 out ----------------
// grid (4, 8, 24), 256 thr. 128x128 tile, BK=32, 16x16x32 bf16 MFMA.
// out[row][col] = sum_k X[row][k] * Wcat[k][col],  X = [zr|zi] (K=1024),
// Wcat second half carries sgn (applied via bf16 sign-bit XOR at staging).
__global__ __launch_bounds__(256) void k_qkv(float* __restrict__ ws) {
  __shared__ __align__(16) unsigned short Ah[128 * 32], Al[128 * 32];
  __shared__ __align__(16) unsigned short Bh[128 * 32], Bl[128 * 32];
  const unsigned short* xh = (const unsigned short*)(ws + OFF_XH);
  const unsigned short* xl = (const unsigned short*)(ws + OFF_XL);
  const unsigned short* wh = (const unsigned short*)(ws + OFF_WH);
  const unsigned short* wl = (const unsigned short*)(ws + OFF_WL);
  int g = blockIdx.z, m = g / 6, w6 = g % 6;
  int off;
  switch (w6) {
    case 0:  off = OFF_QR; break;
    case 1:  off = OFF_QI; break;
    case 2:  off = OFF_KR; break;
    case 3:  off = OFF_KI; break;
    case 4:  off = OFF_VR; break;
    default: off = OFF_VI; break;
  }
  float* out = ws + off + m * BSD;
  // plane selection: pair base (w6>>1)*2; first half of K uses plane p1, second p2 with sign
  int pair = (w6 >> 1) * 2;
  int p1 = m * 6 + pair + (w6 & 1);
  int p2 = m * 6 + pair + ((w6 & 1) ^ 1);
  unsigned int xmask = (w6 & 1) ? 0u : 0x80008000u;   // sgn=-1 for w6 even, on K>=512 half
  const unsigned short* BH1 = wh + (size_t)p1 * 262144;
  const unsigned short* BL1 = wl + (size_t)p1 * 262144;
  const unsigned short* BH2 = wh + (size_t)p2 * 262144;
  const unsigned short* BL2 = wl + (size_t)p2 * 262144;

  int row0 = blockIdx.y * 128, col0 = blockIdx.x * 128;
  int t = threadIdx.x, lane = t & 63, w = t >> 6;
  int wr = w >> 1, wc = w & 1;
  int q = lane >> 4, r = lane & 15;
  int srow = t >> 2;            // 0..63 (and +64)
  int skoff = (t & 3) * 8;      // element offset within 32-k chunk (16B granule)
  size_t arow1 = (size_t)(row0 + srow) * 1024 + skoff;
  size_t arow2 = (size_t)(row0 + 64 + srow) * 1024 + skoff;
  size_t brow1 = (size_t)(col0 + srow) * 512 + skoff;
  size_t brow2 = (size_t)(col0 + 64 + srow) * 512 + skoff;

  floatx4 acc[4][4];
#pragma unroll
  for (int i = 0; i < 4; ++i)
#pragma unroll
    for (int j = 0; j < 4; ++j) acc[i][j] = (floatx4){0.f, 0.f, 0.f, 0.f};

  for (int k0 = 0; k0 < 1024; k0 += 32) {
    // ---- A staging (hi/lo), rows srow & srow+64
    uint4 a0h = *(const uint4*)(xh + arow1 + k0);
    uint4 a1h = *(const uint4*)(xh + arow2 + k0);
    uint4 a0l = *(const uint4*)(xl + arow1 + k0);
    uint4 a1l = *(const uint4*)(xl + arow2 + k0);
    // ---- B staging with K-half plane select + sign
    const unsigned short *BgH, *BgL;
    unsigned int xm;
    int kk = k0;
    if (k0 < 512) { BgH = BH1; BgL = BL1; xm = 0u; }
    else          { BgH = BH2; BgL = BL2; xm = xmask; kk = k0 - 512; }
    uint4 b0h = *(const uint4*)(BgH + brow1 + kk);
    uint4 b1h = *(const uint4*)(BgH + brow2 + kk);
    uint4 b0l = *(const uint4*)(BgL + brow1 + kk);
    uint4 b1l = *(const uint4*)(BgL + brow2 + kk);
    b0h.x ^= xm; b0h.y ^= xm; b0h.z ^= xm; b0h.w ^= xm;
    b1h.x ^= xm; b1h.y ^= xm; b1h.z ^= xm; b1h.w ^= xm;
    b0l.x ^= xm; b0l.y ^= xm; b0l.z ^= xm; b0l.w ^= xm;
    b1l.x ^= xm; b1l.y ^= xm; b1l.z ^= xm; b1l.w ^= xm;
    *(uint4*)(Ah + srow * 32 + skoff) = a0h;
    *(uint4*)(Ah + (64 + srow) * 32 + skoff) = a1h;
    *(uint4*)(Al + srow * 32 + skoff) = a0l;
    *(uint4*)(Al + (64 + srow) * 32 + skoff) = a1l;
    *(uint4*)(Bh + srow * 32 + skoff) = b0h;
    *(uint4*)(Bh + (64 + srow) * 32 + skoff) = b1h;
    *(uint4*)(Bl + srow * 32 + skoff) = b0l;
    *(uint4*)(Bl + (64 + srow) * 32 + skoff) = b1l;
    __syncthreads();
    s8v ah[4], al[4], bh[4], bl[4];
#pragma unroll
    for (int i = 0; i < 4; ++i) {
      int ro = (wr * 64 + i * 16 + r) * 32 + q * 8;
      ah[i] = *(const s8v*)((const short*)Ah + ro);
      al[i] = *(const s8v*)((const short*)Al + ro);
    }
#pragma unroll
    for (int j = 0; j < 4; ++j) {
      int ro = (wc * 64 + j * 16 + r) * 32 + q * 8;
      bh[j] = *(const s8v*)((const short*)Bh + ro);
      bl[j] = *(const s8v*)((const short*)Bl + ro);
    }
#pragma unroll
    for (int i = 0; i < 4; ++i)
#pragma unroll
      for (int j = 0; j < 4; ++j) {
        acc[i][j] = __builtin_amdgcn_mfma_f32_16x16x32_bf16(ah[i], bh[j], acc[i][j], 0, 0, 0);
        acc[i][j] = __builtin_amdgcn_mfma_f32_16x16x32_bf16(ah[i], bl[j], acc[i][j], 0, 0, 0);
        acc[i][j] = __builtin_amdgcn_mfma_f32_16x16x32_bf16(al[i], bh[j], acc[i][j], 0, 0, 0);
      }
    __syncthreads();
  }
#pragma unroll
  for (int i = 0; i < 4; ++i)
#pragma unroll
    for (int j = 0; j < 4; ++j) {
      int rowb = row0 + wr * 64 + i * 16 + q * 4;
      int colb = col0 + wc * 64 + j * 16 + r;
#pragma unroll
      for (int reg = 0; reg < 4; ++reg)
        out[(size_t)(rowb + reg) * 512 + colb] = acc[i][j][reg];
    }
}

// ---------------- scores + row softmax (R1 fp32) ----------------
__global__ __launch_bounds__(256) void k_attn(float* __restrict__ ws) {
  __shared__ float Qr[16][36], Qi[16][36], Kr[16][132], Ki[16][132];
  int stile = blockIdx.x, mb = blockIdx.y;
  int t = threadIdx.x, ty = t >> 5, tx = t & 31;
  const float* qr = ws + OFF_QR + (mb * S + stile * 32) * D;
  const float* qi = ws + OFF_QI + (mb * S + stile * 32) * D;
  const float* kr = ws + OFF_KR + mb * S * D;
  const float* ki = ws + OFF_KI + mb * S * D;
  float acc[4][4] = {};
  int qrow = t >> 3, qk = (t & 7) * 2;
  int krow = t >> 2, kk4 = (t & 3) * 4;
  for (int k0 = 0; k0 < D; k0 += 16) {
    float2 q2 = *(const float2*)(qr + qrow * D + k0 + qk);
    Qr[qk][qrow] = q2.x; Qr[qk + 1][qrow] = q2.y;
    q2 = *(const float2*)(qi + qrow * D + k0 + qk);
    Qi[qk][qrow] = q2.x; Qi[qk + 1][qrow] = q2.y;
#pragma unroll
    for (int rr = 0; rr < 2; ++rr) {
      int row = krow + rr * 64;
      float4 k4 = *(const float4*)(kr + row * D + k0 + kk4);
      Kr[kk4][row] = k4.x; Kr[kk4 + 1][row] = k4.y; Kr[kk4 + 2][row] = k4.z; Kr[kk4 + 3][row] = k4.w;
      k4 = *(const float4*)(ki + row * D + k0 + kk4);
      Ki[kk4][row] = k4.x; Ki[kk4 + 1][row] = k4.y; Ki[kk4 + 2][row] = k4.z; Ki[kk4 + 3][row] = k4.w;
    }
    __syncthreads();
#pragma unroll
    for (int kk = 0; kk < 16; ++kk) {
      float4 a1 = *(const float4*)&Qr[kk][ty * 4];
      float4 a2 = *(const float4*)&Qi[kk][ty * 4];
      float4 b1 = *(const float4*)&Kr[kk][tx * 4];
      float4 b2 = *(const float4*)&Ki[kk][tx * 4];
      float av1[4] = {a1.x, a1.y, a1.z, a1.w}, av2[4] = {a2.x, a2.y, a2.z, a2.w};
      float bv1[4] = {b1.x, b1.y, b1.z, b1.w}, bv2[4] = {b2.x, b2.y, b2.z, b2.w};
#pragma unroll
      for (int i = 0; i < 4; ++i)
#pragma unroll
        for (int j = 0; j < 4; ++j)
          acc[i][j] += av1[i] * bv1[j] + av2[i] * bv2[j];
    }
    __syncthreads();
  }
  float* attn = ws + OFF_ATTN + mb * S * S;
#pragma unroll
  for (int i = 0; i < 4; ++i) {
    int srow = stile * 32 + ty * 4 + i;
    float v[4];
    float mx = -1e30f;
#pragma unroll
    for (int j = 0; j < 4; ++j) { v[j] = acc[i][j] * SCALE; mx = fmaxf(mx, v[j]); }
    for (int o = 1; o < 32; o <<= 1) mx = fmaxf(mx, __shfl_xor(mx, o));
    float sm = 0.f;
#pragma unroll
    for (int j = 0; j < 4; ++j) { v[j] = __expf(v[j] - mx); sm += v[j]; }
    for (int o = 1; o < 32; o <<= 1) sm += __shfl_xor(sm, o);
    float inv = 1.f / sm;
    float4 o4 = {v[0] * inv, v[1] * inv, v[2] * inv, v[3] * inv};
    *(float4*)(attn + srow * S + tx * 4) = o4;
  }
}

// ---------------- PV (R1 fp32) ----------------
__global__ __launch_bounds__(256) void k_pv(float* __restrict__ ws) {
  __shared__ float Ps[16][36], Vr[16][64], Vi[16][64];
  int ex = blockIdx.x * 64, sy = blockIdx.y * 32, mb = blockIdx.z;
  int t = threadIdx.x, ty = t >> 5, tx = t & 31;
  const float* attn = ws + OFF_ATTN + (mb * S + sy) * S;
  const float* vr = ws + OFF_VR + mb * S * D + ex;
  const float* vi = ws + OFF_VI + mb * S * D + ex;
  float ar_[4][2] = {}, ai_[4][2] = {};
  int prow = t >> 3, pk = (t & 7) * 2;
  int vk = t >> 4, ve = (t & 15) * 4;
  for (int k0 = 0; k0 < S; k0 += 16) {
    float2 p2 = *(const float2*)(attn + prow * S + k0 + pk);
    Ps[pk][prow] = p2.x; Ps[pk + 1][prow] = p2.y;
    float4 v4 = *(const float4*)(vr + (k0 + vk) * D + ve);
    *(float4*)&Vr[vk][ve] = v4;
    v4 = *(const float4*)(vi + (k0 + vk) * D + ve);
    *(float4*)&Vi[vk][ve] = v4;
    __syncthreads();
#pragma unroll
    for (int kk = 0; kk < 16; ++kk) {
      float4 a = *(const float4*)&Ps[kk][ty * 4];
      float2 br = *(const float2*)&Vr[kk][tx * 2];
      float2 bi = *(const float2*)&Vi[kk][tx * 2];
      float av[4] = {a.x, a.y, a.z, a.w};
#pragma unroll
      for (int i = 0; i < 4; ++i) {
        ar_[i][0] += av[i] * br.x; ar_[i][1] += av[i] * br.y;
        ai_[i][0] += av[i] * bi.x; ai_[i][1] += av[i] * bi.y;
      }
    }
    __syncthreads();
  }
  float* orp = ws + OFF_OR + (mb * S + sy) * D + ex;
  float* oip = ws + OFF_OI + (mb * S + sy) * D + ex;
#pragma unroll
  for (int i = 0; i < 4; ++i) {
    float2 o1 = {ar_[i][0], ar_[i][1]};
    float2 o2 = {ai_[i][0], ai_[i][1]};
    *(float2*)(orp + (ty * 4 + i) * D + tx * 2) = o1;
    *(float2*)(oip + (ty * 4 + i) * D + tx * 2) = o2;
  }
}

// ---------------- ModReLU + ComplexLayerNorm (R1) ----------------
__global__ __launch_bounds__(64) void k_modln(float* __restrict__ ws,
                                              const float* __restrict__ mod_bias,
                                              const float* __restrict__ ln_scale,
                                              const float* __restrict__ ln_shift) {
  int blk = blockIdx.x;
  int m = blk / (B * S);
  int t = threadIdx.x;
  float* orp = ws + OFF_OR + (size_t)blk * D;
  float* oip = ws + OFF_OI + (size_t)blk * D;
  float orv[2][4], oiv[2][4], magv[2][4];
  float sum = 0.f, sumsq = 0.f;
#pragma unroll
  for (int k = 0; k < 2; ++k) {
    float4 a = *(const float4*)(orp + t * 4 + k * 256);
    float4 c = *(const float4*)(oip + t * 4 + k * 256);
    float av[4] = {a.x, a.y, a.z, a.w}, cv[4] = {c.x, c.y, c.z, c.w};
#pragma unroll
    for (int j = 0; j < 4; ++j) {
      int e = t * 4 + k * 256 + j;
      float o_r = av[j], o_i = cv[j];
      float mag = sqrtf(o_r * o_r + o_i * o_i) + EPS;
      float g = fmaxf(mag + mod_bias[m * D + e], 0.f) / mag;
      o_r *= g; o_i *= g;
      orv[k][j] = o_r; oiv[k][j] = o_i;
      float mag2 = sqrtf(o_r * o_r + o_i * o_i) + EPS;
      magv[k][j] = mag2;
      sum += mag2;
      sumsq += mag2 * mag2;
    }
  }
  for (int o = 1; o < 64; o <<= 1) {
    sum += __shfl_xor(sum, o);
    sumsq += __shfl_xor(sumsq, o);
  }
  float mu = sum * (1.f / D);
  float var = (sumsq - (float)D * mu * mu) * (1.f / (D - 1));
  float inv = 1.f / sqrtf(var + EPS);
#pragma unroll
  for (int k = 0; k < 2; ++k) {
#pragma unroll
    for (int j = 0; j < 4; ++j) {
      int e = t * 4 + k * 256 + j;
      float nm = (magv[k][j] - mu) * inv * ln_scale[m * D + e] + ln_shift[m * D + e];
      float hyp = magv[k][j] - EPS;
      float cp, sp;
      if (hyp > 0.f) { cp = orv[k][j] / hyp; sp = oiv[k][j] / hyp; }
      else           { cp = 1.f;             sp = 0.f; }
      orv[k][j] = nm * cp;
      oiv[k][j] = nm * sp;
    }
    float4 a = {orv[k][0], orv[k][1], orv[k][2], orv[k][3]};
    float4 c = {oiv[k][0], oiv[k][1], oiv[k][2], oiv[k][3]};
    *(float4*)(orp + t * 4 + k * 256) = a;
    *(float4*)(oip + t * 4 + k * 256) = c;
  }
}

// ---------------- feat (R1) ----------------
__global__ __launch_bounds__(256) void k_feat(float* __restrict__ ws) {
  int idx = blockIdx.x * 256 + threadIdx.x;
  int mb = idx >> 10;
  int f = idx & 1023;
  const float* src = ws + ((f < D) ? OFF_OR : OFF_OI) + mb * S * D + ((f < D) ? f : f - D);
  float s = 0.f;
#pragma unroll 8
  for (int ss = 0; ss < S; ++ss) s += src[ss * D];
  ws[OFF_FEAT + idx] = s * (1.0f / S);
}

// ---------------- wsel (R1) ----------------
__global__ __launch_bounds__(256) void k_wsel(float* __restrict__ ws,
                                              const float* __restrict__ hnew,
                                              const float* __restrict__ bias_W,
                                              const float* __restrict__ bias_b,
                                              const float* __restrict__ w_sal) {
  __shared__ float mb_s[B][M];
  __shared__ float sal_s[M][B];
  int t = threadIdx.x;
  int p = t >> 3, l = t & 7;
  {
    int b = p >> 2, m = p & 3;
    float s = 0.f;
    for (int d2 = l; d2 < D; d2 += 8) s += hnew[b * D + d2] * bias_W[d2 * M + m];
    for (int o = 1; o < 8; o <<= 1) s += __shfl_xor(s, o);
    if (l == 0) mb_s[b][m] = s + bias_b[m];
  }
  {
    int m = p >> 3, b = p & 7;
    float s = 0.f;
    for (int f = l; f < 2 * D; f += 8) s += ws[OFF_FEAT + (m * B + b) * 2 * D + f] * w_sal[m * 2 * D + f];
    for (int o = 1; o < 8; o <<= 1) s += __shfl_xor(s, o);
    if (l == 0) sal_s[m][b] = s;
  }
  __syncthreads();
  if (t < B) {
    int b = t;
    float lg[M], mx = -1e30f;
#pragma unroll
    for (int m = 0; m < M; ++m) { lg[m] = sal_s[m][b] + mb_s[b][m]; mx = fmaxf(mx, lg[m]); }
    float sm = 0.f;
#pragma unroll
    for (int m = 0; m < M; ++m) { lg[m] = expf(lg[m] - mx); sm += lg[m]; }
    float inv = 1.f / sm;
#pragma unroll
    for (int m = 0; m < M; ++m) ws[OFF_W + m * B + b] = lg[m] * inv;
  }
}

// ---------------- bcast (R1 fp32) + bf16 hi/lo Xcat refresh ----------------
__global__ __launch_bounds__(256) void k_bcast(float* __restrict__ ws) {
  unsigned short* xh = (unsigned short*)(ws + OFF_XH);
  unsigned short* xl = (unsigned short*)(ws + OFF_XL);
  int i4 = blockIdx.x * 256 + threadIdx.x;
  int b = i4 >> 14;
  float w0 = ws[OFF_W + 0 * B + b], w1 = ws[OFF_W + 1 * B + b];
  float w2 = ws[OFF_W + 2 * B + b], w3 = ws[OFF_W + 3 * B + b];
  const float4* mr = (const float4*)(ws + OFF_OR);
  const float4* mi = (const float4*)(ws + OFF_OI);
  const int MS = BSD / 4;
  int row = i4 >> 7;
  int d4 = (i4 & 127) * 4;
  float4 r0 = mr[i4], r1 = mr[i4 + MS], r2 = mr[i4 + 2 * MS], r3 = mr[i4 + 3 * MS];
  float gv[4];
  gv[0] = w0 * r0.x + w1 * r1.x + w2 * r2.x + w3 * r3.x;
  gv[1] = w0 * r0.y + w1 * r1.y + w2 * r2.y + w3 * r3.y;
  gv[2] = w0 * r0.z + w1 * r1.z + w2 * r2.z + w3 * r3.z;
  gv[3] = w0 * r0.w + w1 * r1.w + w2 * r2.w + w3 * r3.w;
  ((float4*)(ws + OFF_ZR))[i4] = (float4){gv[0], gv[1], gv[2], gv[3]};
  us4 hh, hl;
#pragma unroll
  for (int j = 0; j < 4; ++j) {
    unsigned short h = f2bf(gv[j]); hh[j] = h; hl[j] = f2bf(gv[j] - bf2f(h));
  }
  *(us4*)(xh + (size_t)row * 1024 + d4) = hh;
  *(us4*)(xl + (size_t)row * 1024 + d4) = hl;
  float4 s0 = mi[i4], s1 = mi[i4 + MS], s2 = mi[i4 + 2 * MS], s3 = mi[i4 + 3 * MS];
  gv[0] = w0 * s0.x + w1 * s1.x + w2 * s2.x + w3 * s3.x;
  gv[1] = w0 * s0.y + w1 * s1.y + w2 * s2.y + w3 * s3.y;
  gv[2] = w0 * s0.z + w1 * s1.z + w2 * s2.z + w3 * s3.z;
  gv[3] = w0 * s0.w + w1 * s1.w + w2 * s2.w + w3 * s3.w;
  ((float4*)(ws + OFF_ZI))[i4] = (float4){gv[0], gv[1], gv[2], gv[3]};
#pragma unroll
  for (int j = 0; j < 4; ++j) {
    unsigned short h = f2bf(gv[j]); hh[j] = h; hl[j] = f2bf(gv[j] - bf2f(h));
  }
  *(us4*)(xh + (size_t)row * 1024 + 512 + d4) = hh;
  *(us4*)(xl + (size_t)row * 1024 + 512 + d4) = hl;
}

// ---------------- halting (R1) ----------------
__global__ __launch_bounds__(256) void k_halt(float* __restrict__ ws,
                                              const float* __restrict__ w_halt,
                                              const float* __restrict__ b_halt) {
  int t = threadIdx.x;
  int b = t >> 5, l = t & 31;
  float s = 0.f;
  for (int f = l; f < 2 * D; f += 32) s += ws[OFF_GWP + b * 2 * D + f] * w_halt[f];
  for (int o = 1; o < 32; o <<= 1) s += __shfl_xor(s, o);
  if (l == 0) {
    float p = 1.f / (1.f + expf(-(s + b_halt[0])));
    float cum = ws[OFF_CUM + b];
    float still = (cum < THRESH) ? 1.f : 0.f;
    bool nh = ((cum + p) >= THRESH) && (cum < THRESH);
    float wt = (nh ? (1.f - cum) : p) * still;
    ws[OFF_CUM + b] = cum + wt;
    ws[OFF_WT + b] = wt;
  }
}

// ---------------- ACT accumulate (R1) ----------------
__global__ __launch_bounds__(256) void k_acc(float* __restrict__ ws) {
  int i4 = blockIdx.x * 256 + threadIdx.x;
  int b = i4 >> 14;
  float wt = ws[OFF_WT + b];
  float4 z = ((const float4*)(ws + OFF_ZR))[i4];
  float4 a = ((float4*)(ws + OFF_AR))[i4];
  a.x += wt * z.x; a.y += wt * z.y; a.z += wt * z.z; a.w += wt * z.w;
  ((float4*)(ws + OFF_AR))[i4] = a;
  z = ((const float4*)(ws + OFF_ZI))[i4];
  a = ((float4*)(ws + OFF_AI))[i4];
  a.x += wt * z.x; a.y += wt * z.y; a.z += wt * z.z; a.w += wt * z.w;
  ((float4*)(ws + OFF_AI))[i4] = a;
}

// ---------------- output (R1) ----------------
__global__ __launch_bounds__(256) void k_out(const float* __restrict__ ws,
                                             float* __restrict__ out) {
  int i4 = blockIdx.x * 256 + threadIdx.x;
  ((float4*)out)[i4] = ((const float4*)(ws + OFF_AR))[i4];
  ((float4*)out)[i4 + BSD / 4] = ((const float4*)(ws + OFF_AI))[i4];
}

extern "C" void kernel_launch(void* const* d_in, const int* in_sizes, int n_in,
                              void* d_out, int out_size, void* d_ws, size_t ws_size,
                              hipStream_t stream) {
  (void)in_sizes; (void)n_in; (void)out_size; (void)ws_size;
  const float* x_real  = (const float*)d_in[0];
  const float* x_imag  = (const float*)d_in[1];
  const float* Wq_r    = (const float*)d_in[2];
  const float* Wq_i    = (const float*)d_in[3];
  const float* Wk_r    = (const float*)d_in[4];
  const float* Wk_i    = (const float*)d_in[5];
  const float* Wv_r    = (const float*)d_in[6];
  const float* Wv_i    = (const float*)d_in[7];
  const float* mod_bias = (const float*)d_in[8];
  const float* ln_scale = (const float*)d_in[9];
  const float* ln_shift = (const float*)d_in[10];
  const float* w_sal   = (const float*)d_in[11];
  const float* gru_Wih = (const float*)d_in[12];
  const float* gru_Whh = (const float*)d_in[13];
  const float* gru_bih = (const float*)d_in[14];
  const float* gru_bhh = (const float*)d_in[15];
  const float* bias_W  = (const float*)d_in[16];
  const float* bias_b  = (const float*)d_in[17];
  const float* w_halt  = (const float*)d_in[18];
  const float* b_halt  = (const float*)d_in[19];
  float* ws = (float*)d_ws;
  float* out = (float*)d_out;

  k_wprep<<<dim3(8, 8, 24), 256, 0, stream>>>(Wq_r, Wq_i, Wk_r, Wk_i, Wv_r, Wv_i, ws);
  k_init<<<512, 256, 0, stream>>>(x_real, x_imag, ws);
  k_gwp<<<32, 256, 0, stream>>>(ws + OFF_ZR, ws + OFF_ZI, ws + OFF_GWP);
  for (int step = 0; step < DEPTH; ++step) {
    const float* hold = ws + ((step & 1) ? OFF_H1 : OFF_H0);
    float* hnew = ws + ((step & 1) ? OFF_H0 : OFF_H1);
    k_gru<<<dim3(4, 8), 128, 0, stream>>>(ws + OFF_GWP, hold, hnew,
                                          gru_Wih, gru_Whh, gru_bih, gru_bhh);
    k_qkv<<<dim3(4, 8, 24), 256, 0, stream>>>(ws);
    k_attn<<<dim3(4, 32), 256, 0, stream>>>(ws);
    k_pv<<<dim3(8, 4, 32), 256, 0, stream>>>(ws);
    k_modln<<<M * B * S, 64, 0, stream>>>(ws, mod_bias, ln_scale, ln_shift);
    k_feat<<<256, 256, 0, stream>>>(ws);
    k_wsel<<<1, 256, 0, stream>>>(ws, hnew, bias_W, bias_b, w_sal);
    k_bcast<<<512, 256, 0, stream>>>(ws);
    k_gwp<<<32, 256, 0, stream>>>(ws + OFF_ZR, ws + OFF_ZI, ws + OFF_GWP);
    k_halt<<<1, 256, 0, stream>>>(ws, w_halt, b_halt);
    k_acc<<<512, 256, 0, stream>>>(ws);
  }
  k_out<<<512, 256, 0, stream>>>(ws, out);
}

// Round 7
// 4864.589 us; speedup vs baseline: 2.5794x; 1.3010x over previous
//
#include <hip/hip_runtime.h>
#include <math.h>

#define B 8
#define S 128
#define D 512
#define M 4
#define BS 1024
#define BSD 524288          // B*S*D
#define DEPTH 16
#define THRESH 0.9999f
#define EPS 1e-6f
#define SCALE 0.04419417382415922f   // D^-0.5

typedef float floatx4 __attribute__((ext_vector_type(4)));
typedef short s8v __attribute__((ext_vector_type(8)));
typedef unsigned short us4 __attribute__((ext_vector_type(4)));

__device__ __forceinline__ unsigned short f2bf(float f) {
  unsigned int u = __float_as_uint(f);
  u += 0x7FFFu + ((u >> 16) & 1u);          // round-to-nearest-even
  return (unsigned short)(u >> 16);
}
__device__ __forceinline__ float bf2f(unsigned short h) {
  return __uint_as_float((unsigned int)h << 16);
}

// ---------------- workspace layout (float-slot offsets) — R1 base + bf16 annex ----------------
#define OFF_ZR   0
#define OFF_ZI   (1*BSD)
#define OFF_AR   (2*BSD)
#define OFF_AI   (3*BSD)
#define OFF_QR   (4*BSD)    // each of q/k/v r/i fp32: M*BSD = 4*BSD
#define OFF_QI   (8*BSD)
#define OFF_KR   (12*BSD)
#define OFF_KI   (16*BSD)
#define OFF_VR   (20*BSD)
#define OFF_VI   (24*BSD)
#define OFF_OR   (28*BSD)
#define OFF_OI   (32*BSD)
#define OFF_ATTN (36*BSD)
#define OFF_FEAT (37*BSD)
#define OFF_GWP  (37*BSD + 65536)
#define OFF_H0   (37*BSD + 73728)
#define OFF_H1   (37*BSD + 77824)
#define OFF_CUM  (37*BSD + 81920)
#define OFF_W    (37*BSD + 81928)
#define OFF_WT   (37*BSD + 81960)
// bf16 annex. xcat hi/lo: [1024][1024] bf16 = BSD slots each.
// Weight planes: 24 matrices (m*6+{qr,qi,kr,ki,vr,vi}) of [512 n][512 k] bf16, hi & lo = 6*BSD slots each.
#define OFF_XH   (37*BSD + 90112)
#define OFF_XL   (OFF_XH + 1*BSD)
#define OFF_WH   (OFF_XH + 2*BSD)
#define OFF_WL   (OFF_XH + 8*BSD)
// end = 51*BSD + 90112 slots ~ 107.3 MB (functioned in R6)

// ---------------- init: fp32 carry + bf16 hi/lo Xcat ----------------
__global__ __launch_bounds__(256) void k_init(const float* __restrict__ xr,
                                              const float* __restrict__ xi,
                                              float* __restrict__ ws) {
  unsigned short* xh = (unsigned short*)(ws + OFF_XH);
  unsigned short* xl = (unsigned short*)(ws + OFF_XL);
  int i4 = blockIdx.x * 256 + threadIdx.x;      // BSD/4
  float4 a = ((const float4*)xr)[i4];
  float4 b = ((const float4*)xi)[i4];
  ((float4*)(ws + OFF_ZR))[i4] = a;
  ((float4*)(ws + OFF_ZI))[i4] = b;
  float4 z = {0.f, 0.f, 0.f, 0.f};
  ((float4*)(ws + OFF_AR))[i4] = z;
  ((float4*)(ws + OFF_AI))[i4] = z;
  int row = i4 >> 7;
  int d4 = (i4 & 127) * 4;
  float av[4] = {a.x, a.y, a.z, a.w}, bv[4] = {b.x, b.y, b.z, b.w};
  us4 hh, hl;
#pragma unroll
  for (int j = 0; j < 4; ++j) {
    unsigned short h = f2bf(av[j]); hh[j] = h; hl[j] = f2bf(av[j] - bf2f(h));
  }
  *(us4*)(xh + (size_t)row * 1024 + d4) = hh;
  *(us4*)(xl + (size_t)row * 1024 + d4) = hl;
#pragma unroll
  for (int j = 0; j < 4; ++j) {
    unsigned short h = f2bf(bv[j]); hh[j] = h; hl[j] = f2bf(bv[j] - bf2f(h));
  }
  *(us4*)(xh + (size_t)row * 1024 + 512 + d4) = hh;
  *(us4*)(xl + (size_t)row * 1024 + 512 + d4) = hl;
  if (i4 < (B * D) / 4) {
    ((float4*)(ws + OFF_H0))[i4] = z;
    ((float4*)(ws + OFF_H1))[i4] = z;
  }
  if (i4 < B) ws[OFF_CUM + i4] = 0.f;
}

// ---------------- weight prep: transpose each W[m] -> [n][k] bf16 hi/lo planes ----------------
// grid (8, 8, 24): 64k x 64n tiles; z = m*6+idx, idx in {qr,qi,kr,ki,vr,vi}
__global__ __launch_bounds__(256) void k_wprep(const float* __restrict__ Wqr,
                                               const float* __restrict__ Wqi,
                                               const float* __restrict__ Wkr,
                                               const float* __restrict__ Wki,
                                               const float* __restrict__ Wvr,
                                               const float* __restrict__ Wvi,
                                               float* __restrict__ ws) {
  __shared__ float lt[64][65];
  unsigned short* wh = (unsigned short*)(ws + OFF_WH);
  unsigned short* wl = (unsigned short*)(ws + OFF_WL);
  int z = blockIdx.z, m = z / 6, idx = z % 6;
  const float* Wsrc;
  switch (idx) {
    case 0:  Wsrc = Wqr; break;
    case 1:  Wsrc = Wqi; break;
    case 2:  Wsrc = Wkr; break;
    case 3:  Wsrc = Wki; break;
    case 4:  Wsrc = Wvr; break;
    default: Wsrc = Wvi; break;
  }
  Wsrc += (size_t)m * D * D;
  int k0 = blockIdx.x * 64, n0 = blockIdx.y * 64;
  int tx = threadIdx.x & 63, ty = threadIdx.x >> 6;
#pragma unroll
  for (int i = 0; i < 16; ++i) {
    int kl = ty + i * 4;
    lt[kl][tx] = Wsrc[(size_t)(k0 + kl) * D + n0 + tx];
  }
  __syncthreads();
  unsigned short* whp = wh + (size_t)z * 262144;
  unsigned short* wlp = wl + (size_t)z * 262144;
#pragma unroll
  for (int i = 0; i < 16; ++i) {
    int nl = ty + i * 4;
    float v = lt[tx][nl];
    unsigned short h = f2bf(v);
    whp[(size_t)(n0 + nl) * 512 + k0 + tx] = h;
    wlp[(size_t)(n0 + nl) * 512 + k0 + tx] = f2bf(v - bf2f(h));
  }
}

// ---------------- gwp (R1) ----------------
__global__ __launch_bounds__(256) void k_gwp(const float* __restrict__ zr,
                                             const float* __restrict__ zi,
                                             float* __restrict__ gwp) {
  int idx = blockIdx.x * 256 + threadIdx.x;
  int b = idx >> 10;
  int f = idx & 1023;
  const float* src = (f < D) ? (zr + b * S * D + f) : (zi + b * S * D + (f - D));
  float s = 0.f;
#pragma unroll 8
  for (int ss = 0; ss < S; ++ss) s += src[ss * D];
  gwp[idx] = s * (1.0f / S);
}

// ---------------- GRU: k-split reduction GEMM ----------------
// grid (8, 8): x = 64-wide d-chunk, y = batch. 256 thr = 4 waves; wave ks covers
// unified-K slice [ks*384, +384) of K=1536 ([pooled@Wih | h@Whh]).
// Gate columns in W: [r | z | n], each 512 wide; xn/hn kept separate for n-gate.
__global__ __launch_bounds__(256) void k_gru(const float* __restrict__ gwp,
                                             const float* __restrict__ hold,
                                             float* __restrict__ hnew,
                                             const float* __restrict__ Wih,
                                             const float* __restrict__ Whh,
                                             const float* __restrict__ bih,
                                             const float* __restrict__ bhh) {
  __shared__ float xbuf[1024];
  __shared__ float hbuf[512];
  __shared__ float red[4][64][4];
  int b = blockIdx.y;
  int t = threadIdx.x;
  int td = t & 63, ks = t >> 6;
  int c0 = blockIdx.x * 64;
  for (int f = t; f < 1024; f += 256) xbuf[f] = gwp[b * 1024 + f];
  for (int d2 = t; d2 < 512; d2 += 256) hbuf[d2] = hold[b * 512 + d2];
  __syncthreads();
  float accR = 0.f, accZ = 0.f, accXn = 0.f, accHn = 0.f;
  int kbeg = ks * 384, kend = kbeg + 384;
#pragma unroll 4
  for (int kk = kbeg; kk < kend; ++kk) {
    bool ih = kk < 1024;                         // wave-uniform scalar branch
    float x = ih ? xbuf[kk] : hbuf[kk - 1024];
    const float* base = ih ? (Wih + (size_t)kk * 1536) : (Whh + (size_t)(kk - 1024) * 1536);
    float wr = base[c0 + td];
    float wz = base[512 + c0 + td];
    float wn = base[1024 + c0 + td];
    accR += x * wr;
    accZ += x * wz;
    if (ih) accXn += x * wn; else accHn += x * wn;
  }
  red[ks][td][0] = accR;
  red[ks][td][1] = accZ;
  red[ks][td][2] = accXn;
  red[ks][td][3] = accHn;
  __syncthreads();
  if (t < 64) {
    int c = c0 + t;
    float r_ = 0.f, z_ = 0.f, xn = 0.f, hn = 0.f;
#pragma unroll
    for (int s = 0; s < 4; ++s) {
      r_ += red[s][t][0]; z_ += red[s][t][1]; xn += red[s][t][2]; hn += red[s][t][3];
    }
    r_ += bih[c] + bhh[c];
    z_ += bih[512 + c] + bhh[512 + c];
    xn += bih[1024 + c];
    hn += bhh[1024 + c];
    float r = 1.f / (1.f + expf(-r_));
    float z = 1.f / (1.f + expf(-z_));
    float n = tanhf(xn + r * hn);
    hnew[b * 512 + c] = (1.f - z) * n + z * hbuf[c];
  }
}

// ---------------- QKV: bf16x3 split-MFMA GEMM, fp32 out (R6, proven) ----------------
// grid (4, 8, 24), 256 thr. 128x128 tile, BK=32, 16x16x32 bf16 MFMA.
__global__ __launch_bounds__(256) void k_qkv(float* __restrict__ ws) {
  __shared__ __align__(16) unsigned short Ah[128 * 32], Al[128 * 32];
  __shared__ __align__(16) unsigned short Bh[128 * 32], Bl[128 * 32];
  const unsigned short* xh = (const unsigned short*)(ws + OFF_XH);
  const unsigned short* xl = (const unsigned short*)(ws + OFF_XL);
  const unsigned short* wh = (const unsigned short*)(ws + OFF_WH);
  const unsigned short* wl = (const unsigned short*)(ws + OFF_WL);
  int g = blockIdx.z, m = g / 6, w6 = g % 6;
  int off;
  switch (w6) {
    case 0:  off = OFF_QR; break;
    case 1:  off = OFF_QI; break;
    case 2:  off = OFF_KR; break;
    case 3:  off = OFF_KI; break;
    case 4:  off = OFF_VR; break;
    default: off = OFF_VI; break;
  }
  float* out = ws + off + m * BSD;
  int pair = (w6 >> 1) * 2;
  int p1 = m * 6 + pair + (w6 & 1);
  int p2 = m * 6 + pair + ((w6 & 1) ^ 1);
  unsigned int xmask = (w6 & 1) ? 0u : 0x80008000u;   // sgn=-1 for w6 even, on K>=512 half
  const unsigned short* BH1 = wh + (size_t)p1 * 262144;
  const unsigned short* BL1 = wl + (size_t)p1 * 262144;
  const unsigned short* BH2 = wh + (size_t)p2 * 262144;
  const unsigned short* BL2 = wl + (size_t)p2 * 262144;

  int row0 = blockIdx.y * 128, col0 = blockIdx.x * 128;
  int t = threadIdx.x, lane = t & 63, w = t >> 6;
  int wr = w >> 1, wc = w & 1;
  int q = lane >> 4, r = lane & 15;
  int srow = t >> 2;
  int skoff = (t & 3) * 8;
  size_t arow1 = (size_t)(row0 + srow) * 1024 + skoff;
  size_t arow2 = (size_t)(row0 + 64 + srow) * 1024 + skoff;
  size_t brow1 = (size_t)(col0 + srow) * 512 + skoff;
  size_t brow2 = (size_t)(col0 + 64 + srow) * 512 + skoff;

  floatx4 acc[4][4];
#pragma unroll
  for (int i = 0; i < 4; ++i)
#pragma unroll
    for (int j = 0; j < 4; ++j) acc[i][j] = (floatx4){0.f, 0.f, 0.f, 0.f};

  for (int k0 = 0; k0 < 1024; k0 += 32) {
    uint4 a0h = *(const uint4*)(xh + arow1 + k0);
    uint4 a1h = *(const uint4*)(xh + arow2 + k0);
    uint4 a0l = *(const uint4*)(xl + arow1 + k0);
    uint4 a1l = *(const uint4*)(xl + arow2 + k0);
    const unsigned short *BgH, *BgL;
    unsigned int xm;
    int kk = k0;
    if (k0 < 512) { BgH = BH1; BgL = BL1; xm = 0u; }
    else          { BgH = BH2; BgL = BL2; xm = xmask; kk = k0 - 512; }
    uint4 b0h = *(const uint4*)(BgH + brow1 + kk);
    uint4 b1h = *(const uint4*)(BgH + brow2 + kk);
    uint4 b0l = *(const uint4*)(BgL + brow1 + kk);
    uint4 b1l = *(const uint4*)(BgL + brow2 + kk);
    b0h.x ^= xm; b0h.y ^= xm; b0h.z ^= xm; b0h.w ^= xm;
    b1h.x ^= xm; b1h.y ^= xm; b1h.z ^= xm; b1h.w ^= xm;
    b0l.x ^= xm; b0l.y ^= xm; b0l.z ^= xm; b0l.w ^= xm;
    b1l.x ^= xm; b1l.y ^= xm; b1l.z ^= xm; b1l.w ^= xm;
    *(uint4*)(Ah + srow * 32 + skoff) = a0h;
    *(uint4*)(Ah + (64 + srow) * 32 + skoff) = a1h;
    *(uint4*)(Al + srow * 32 + skoff) = a0l;
    *(uint4*)(Al + (64 + srow) * 32 + skoff) = a1l;
    *(uint4*)(Bh + srow * 32 + skoff) = b0h;
    *(uint4*)(Bh + (64 + srow) * 32 + skoff) = b1h;
    *(uint4*)(Bl + srow * 32 + skoff) = b0l;
    *(uint4*)(Bl + (64 + srow) * 32 + skoff) = b1l;
    __syncthreads();
    s8v ah[4], al[4], bh[4], bl[4];
#pragma unroll
    for (int i = 0; i < 4; ++i) {
      int ro = (wr * 64 + i * 16 + r) * 32 + q * 8;
      ah[i] = *(const s8v*)((const short*)Ah + ro);
      al[i] = *(const s8v*)((const short*)Al + ro);
    }
#pragma unroll
    for (int j = 0; j < 4; ++j) {
      int ro = (wc * 64 + j * 16 + r) * 32 + q * 8;
      bh[j] = *(const s8v*)((const short*)Bh + ro);
      bl[j] = *(const s8v*)((const short*)Bl + ro);
    }
#pragma unroll
    for (int i = 0; i < 4; ++i)
#pragma unroll
      for (int j = 0; j < 4; ++j) {
        acc[i][j] = __builtin_amdgcn_mfma_f32_16x16x32_bf16(ah[i], bh[j], acc[i][j], 0, 0, 0);
        acc[i][j] = __builtin_amdgcn_mfma_f32_16x16x32_bf16(ah[i], bl[j], acc[i][j], 0, 0, 0);
        acc[i][j] = __builtin_amdgcn_mfma_f32_16x16x32_bf16(al[i], bh[j], acc[i][j], 0, 0, 0);
      }
    __syncthreads();
  }
#pragma unroll
  for (int i = 0; i < 4; ++i)
#pragma unroll
    for (int j = 0; j < 4; ++j) {
      int rowb = row0 + wr * 64 + i * 16 + q * 4;
      int colb = col0 + wc * 64 + j * 16 + r;
#pragma unroll
      for (int reg = 0; reg < 4; ++reg)
        out[(size_t)(rowb + reg) * 512 + colb] = acc[i][j][reg];
    }
}

// ---------------- scores + row softmax (R1 fp32) ----------------
__global__ __launch_bounds__(256) void k_attn(float* __restrict__ ws) {
  __shared__ float Qr[16][36], Qi[16][36], Kr[16][132], Ki[16][132];
  int stile = blockIdx.x, mb = blockIdx.y;
  int t = threadIdx.x, ty = t >> 5, tx = t & 31;
  const float* qr = ws + OFF_QR + (mb * S + stile * 32) * D;
  const float* qi = ws + OFF_QI + (mb * S + stile * 32) * D;
  const float* kr = ws + OFF_KR + mb * S * D;
  const float* ki = ws + OFF_KI + mb * S * D;
  float acc[4][4] = {};
  int qrow = t >> 3, qk = (t & 7) * 2;
  int krow = t >> 2, kk4 = (t & 3) * 4;
  for (int k0 = 0; k0 < D; k0 += 16) {
    float2 q2 = *(const float2*)(qr + qrow * D + k0 + qk);
    Qr[qk][qrow] = q2.x; Qr[qk + 1][qrow] = q2.y;
    q2 = *(const float2*)(qi + qrow * D + k0 + qk);
    Qi[qk][qrow] = q2.x; Qi[qk + 1][qrow] = q2.y;
#pragma unroll
    for (int rr = 0; rr < 2; ++rr) {
      int row = krow + rr * 64;
      float4 k4 = *(const float4*)(kr + row * D + k0 + kk4);
      Kr[kk4][row] = k4.x; Kr[kk4 + 1][row] = k4.y; Kr[kk4 + 2][row] = k4.z; Kr[kk4 + 3][row] = k4.w;
      k4 = *(const float4*)(ki + row * D + k0 + kk4);
      Ki[kk4][row] = k4.x; Ki[kk4 + 1][row] = k4.y; Ki[kk4 + 2][row] = k4.z; Ki[kk4 + 3][row] = k4.w;
    }
    __syncthreads();
#pragma unroll
    for (int kk = 0; kk < 16; ++kk) {
      float4 a1 = *(const float4*)&Qr[kk][ty * 4];
      float4 a2 = *(const float4*)&Qi[kk][ty * 4];
      float4 b1 = *(const float4*)&Kr[kk][tx * 4];
      float4 b2 = *(const float4*)&Ki[kk][tx * 4];
      float av1[4] = {a1.x, a1.y, a1.z, a1.w}, av2[4] = {a2.x, a2.y, a2.z, a2.w};
      float bv1[4] = {b1.x, b1.y, b1.z, b1.w}, bv2[4] = {b2.x, b2.y, b2.z, b2.w};
#pragma unroll
      for (int i = 0; i < 4; ++i)
#pragma unroll
        for (int j = 0; j < 4; ++j)
          acc[i][j] += av1[i] * bv1[j] + av2[i] * bv2[j];
    }
    __syncthreads();
  }
  float* attn = ws + OFF_ATTN + mb * S * S;
#pragma unroll
  for (int i = 0; i < 4; ++i) {
    int srow = stile * 32 + ty * 4 + i;
    float v[4];
    float mx = -1e30f;
#pragma unroll
    for (int j = 0; j < 4; ++j) { v[j] = acc[i][j] * SCALE; mx = fmaxf(mx, v[j]); }
    for (int o = 1; o < 32; o <<= 1) mx = fmaxf(mx, __shfl_xor(mx, o));
    float sm = 0.f;
#pragma unroll
    for (int j = 0; j < 4; ++j) { v[j] = __expf(v[j] - mx); sm += v[j]; }
    for (int o = 1; o < 32; o <<= 1) sm += __shfl_xor(sm, o);
    float inv = 1.f / sm;
    float4 o4 = {v[0] * inv, v[1] * inv, v[2] * inv, v[3] * inv};
    *(float4*)(attn + srow * S + tx * 4) = o4;
  }
}

// ---------------- PV (R1 fp32) ----------------
__global__ __launch_bounds__(256) void k_pv(float* __restrict__ ws) {
  __shared__ float Ps[16][36], Vr[16][64], Vi[16][64];
  int ex = blockIdx.x * 64, sy = blockIdx.y * 32, mb = blockIdx.z;
  int t = threadIdx.x, ty = t >> 5, tx = t & 31;
  const float* attn = ws + OFF_ATTN + (mb * S + sy) * S;
  const float* vr = ws + OFF_VR + mb * S * D + ex;
  const float* vi = ws + OFF_VI + mb * S * D + ex;
  float ar_[4][2] = {}, ai_[4][2] = {};
  int prow = t >> 3, pk = (t & 7) * 2;
  int vk = t >> 4, ve = (t & 15) * 4;
  for (int k0 = 0; k0 < S; k0 += 16) {
    float2 p2 = *(const float2*)(attn + prow * S + k0 + pk);
    Ps[pk][prow] = p2.x; Ps[pk + 1][prow] = p2.y;
    float4 v4 = *(const float4*)(vr + (k0 + vk) * D + ve);
    *(float4*)&Vr[vk][ve] = v4;
    v4 = *(const float4*)(vi + (k0 + vk) * D + ve);
    *(float4*)&Vi[vk][ve] = v4;
    __syncthreads();
#pragma unroll
    for (int kk = 0; kk < 16; ++kk) {
      float4 a = *(const float4*)&Ps[kk][ty * 4];
      float2 br = *(const float2*)&Vr[kk][tx * 2];
      float2 bi = *(const float2*)&Vi[kk][tx * 2];
      float av[4] = {a.x, a.y, a.z, a.w};
#pragma unroll
      for (int i = 0; i < 4; ++i) {
        ar_[i][0] += av[i] * br.x; ar_[i][1] += av[i] * br.y;
        ai_[i][0] += av[i] * bi.x; ai_[i][1] += av[i] * bi.y;
      }
    }
    __syncthreads();
  }
  float* orp = ws + OFF_OR + (mb * S + sy) * D + ex;
  float* oip = ws + OFF_OI + (mb * S + sy) * D + ex;
#pragma unroll
  for (int i = 0; i < 4; ++i) {
    float2 o1 = {ar_[i][0], ar_[i][1]};
    float2 o2 = {ai_[i][0], ai_[i][1]};
    *(float2*)(orp + (ty * 4 + i) * D + tx * 2) = o1;
    *(float2*)(oip + (ty * 4 + i) * D + tx * 2) = o2;
  }
}

// ---------------- ModReLU + ComplexLayerNorm (R1) ----------------
__global__ __launch_bounds__(64) void k_modln(float* __restrict__ ws,
                                              const float* __restrict__ mod_bias,
                                              const float* __restrict__ ln_scale,
                                              const float* __restrict__ ln_shift) {
  int blk = blockIdx.x;
  int m = blk / (B * S);
  int t = threadIdx.x;
  float* orp = ws + OFF_OR + (size_t)blk * D;
  float* oip = ws + OFF_OI + (size_t)blk * D;
  float orv[2][4], oiv[2][4], magv[2][4];
  float sum = 0.f, sumsq = 0.f;
#pragma unroll
  for (int k = 0; k < 2; ++k) {
    float4 a = *(const float4*)(orp + t * 4 + k * 256);
    float4 c = *(const float4*)(oip + t * 4 + k * 256);
    float av[4] = {a.x, a.y, a.z, a.w}, cv[4] = {c.x, c.y, c.z, c.w};
#pragma unroll
    for (int j = 0; j < 4; ++j) {
      int e = t * 4 + k * 256 + j;
      float o_r = av[j], o_i = cv[j];
      float mag = sqrtf(o_r * o_r + o_i * o_i) + EPS;
      float g = fmaxf(mag + mod_bias[m * D + e], 0.f) / mag;
      o_r *= g; o_i *= g;
      orv[k][j] = o_r; oiv[k][j] = o_i;
      float mag2 = sqrtf(o_r * o_r + o_i * o_i) + EPS;
      magv[k][j] = mag2;
      sum += mag2;
      sumsq += mag2 * mag2;
    }
  }
  for (int o = 1; o < 64; o <<= 1) {
    sum += __shfl_xor(sum, o);
    sumsq += __shfl_xor(sumsq, o);
  }
  float mu = sum * (1.f / D);
  float var = (sumsq - (float)D * mu * mu) * (1.f / (D - 1));
  float inv = 1.f / sqrtf(var + EPS);
#pragma unroll
  for (int k = 0; k < 2; ++k) {
#pragma unroll
    for (int j = 0; j < 4; ++j) {
      int e = t * 4 + k * 256 + j;
      float nm = (magv[k][j] - mu) * inv * ln_scale[m * D + e] + ln_shift[m * D + e];
      float hyp = magv[k][j] - EPS;
      float cp, sp;
      if (hyp > 0.f) { cp = orv[k][j] / hyp; sp = oiv[k][j] / hyp; }
      else           { cp = 1.f;             sp = 0.f; }
      orv[k][j] = nm * cp;
      oiv[k][j] = nm * sp;
    }
    float4 a = {orv[k][0], orv[k][1], orv[k][2], orv[k][3]};
    float4 c = {oiv[k][0], oiv[k][1], oiv[k][2], oiv[k][3]};
    *(float4*)(orp + t * 4 + k * 256) = a;
    *(float4*)(oip + t * 4 + k * 256) = c;
  }
}

// ---------------- feat (R1) ----------------
__global__ __launch_bounds__(256) void k_feat(float* __restrict__ ws) {
  int idx = blockIdx.x * 256 + threadIdx.x;
  int mb = idx >> 10;
  int f = idx & 1023;
  const float* src = ws + ((f < D) ? OFF_OR : OFF_OI) + mb * S * D + ((f < D) ? f : f - D);
  float s = 0.f;
#pragma unroll 8
  for (int ss = 0; ss < S; ++ss) s += src[ss * D];
  ws[OFF_FEAT + idx] = s * (1.0f / S);
}

// ---------------- wsel (R1) ----------------
__global__ __launch_bounds__(256) void k_wsel(float* __restrict__ ws,
                                              const float* __restrict__ hnew,
                                              const float* __restrict__ bias_W,
                                              const float* __restrict__ bias_b,
                                              const float* __restrict__ w_sal) {
  __shared__ float mb_s[B][M];
  __shared__ float sal_s[M][B];
  int t = threadIdx.x;
  int p = t >> 3, l = t & 7;
  {
    int b = p >> 2, m = p & 3;
    float s = 0.f;
    for (int d2 = l; d2 < D; d2 += 8) s += hnew[b * D + d2] * bias_W[d2 * M + m];
    for (int o = 1; o < 8; o <<= 1) s += __shfl_xor(s, o);
    if (l == 0) mb_s[b][m] = s + bias_b[m];
  }
  {
    int m = p >> 3, b = p & 7;
    float s = 0.f;
    for (int f = l; f < 2 * D; f += 8) s += ws[OFF_FEAT + (m * B + b) * 2 * D + f] * w_sal[m * 2 * D + f];
    for (int o = 1; o < 8; o <<= 1) s += __shfl_xor(s, o);
    if (l == 0) sal_s[m][b] = s;
  }
  __syncthreads();
  if (t < B) {
    int b = t;
    float lg[M], mx = -1e30f;
#pragma unroll
    for (int m = 0; m < M; ++m) { lg[m] = sal_s[m][b] + mb_s[b][m]; mx = fmaxf(mx, lg[m]); }
    float sm = 0.f;
#pragma unroll
    for (int m = 0; m < M; ++m) { lg[m] = expf(lg[m] - mx); sm += lg[m]; }
    float inv = 1.f / sm;
#pragma unroll
    for (int m = 0; m < M; ++m) ws[OFF_W + m * B + b] = lg[m] * inv;
  }
}

// ---------------- bcast (R1 fp32) + bf16 hi/lo Xcat refresh ----------------
__global__ __launch_bounds__(256) void k_bcast(float* __restrict__ ws) {
  unsigned short* xh = (unsigned short*)(ws + OFF_XH);
  unsigned short* xl = (unsigned short*)(ws + OFF_XL);
  int i4 = blockIdx.x * 256 + threadIdx.x;
  int b = i4 >> 14;
  float w0 = ws[OFF_W + 0 * B + b], w1 = ws[OFF_W + 1 * B + b];
  float w2 = ws[OFF_W + 2 * B + b], w3 = ws[OFF_W + 3 * B + b];
  const float4* mr = (const float4*)(ws + OFF_OR);
  const float4* mi = (const float4*)(ws + OFF_OI);
  const int MS = BSD / 4;
  int row = i4 >> 7;
  int d4 = (i4 & 127) * 4;
  float4 r0 = mr[i4], r1 = mr[i4 + MS], r2 = mr[i4 + 2 * MS], r3 = mr[i4 + 3 * MS];
  float gv[4];
  gv[0] = w0 * r0.x + w1 * r1.x + w2 * r2.x + w3 * r3.x;
  gv[1] = w0 * r0.y + w1 * r1.y + w2 * r2.y + w3 * r3.y;
  gv[2] = w0 * r0.z + w1 * r1.z + w2 * r2.z + w3 * r3.z;
  gv[3] = w0 * r0.w + w1 * r1.w + w2 * r2.w + w3 * r3.w;
  ((float4*)(ws + OFF_ZR))[i4] = (float4){gv[0], gv[1], gv[2], gv[3]};
  us4 hh, hl;
#pragma unroll
  for (int j = 0; j < 4; ++j) {
    unsigned short h = f2bf(gv[j]); hh[j] = h; hl[j] = f2bf(gv[j] - bf2f(h));
  }
  *(us4*)(xh + (size_t)row * 1024 + d4) = hh;
  *(us4*)(xl + (size_t)row * 1024 + d4) = hl;
  float4 s0 = mi[i4], s1 = mi[i4 + MS], s2 = mi[i4 + 2 * MS], s3 = mi[i4 + 3 * MS];
  gv[0] = w0 * s0.x + w1 * s1.x + w2 * s2.x + w3 * s3.x;
  gv[1] = w0 * s0.y + w1 * s1.y + w2 * s2.y + w3 * s3.y;
  gv[2] = w0 * s0.z + w1 * s1.z + w2 * s2.z + w3 * s3.z;
  gv[3] = w0 * s0.w + w1 * s1.w + w2 * s2.w + w3 * s3.w;
  ((float4*)(ws + OFF_ZI))[i4] = (float4){gv[0], gv[1], gv[2], gv[3]};
#pragma unroll
  for (int j = 0; j < 4; ++j) {
    unsigned short h = f2bf(gv[j]); hh[j] = h; hl[j] = f2bf(gv[j] - bf2f(h));
  }
  *(us4*)(xh + (size_t)row * 1024 + 512 + d4) = hh;
  *(us4*)(xl + (size_t)row * 1024 + 512 + d4) = hl;
}

// ---------------- halting (R1) ----------------
__global__ __launch_bounds__(256) void k_halt(float* __restrict__ ws,
                                              const float* __restrict__ w_halt,
                                              const float* __restrict__ b_halt) {
  int t = threadIdx.x;
  int b = t >> 5, l = t & 31;
  float s = 0.f;
  for (int f = l; f < 2 * D; f += 32) s += ws[OFF_GWP + b * 2 * D + f] * w_halt[f];
  for (int o = 1; o < 32; o <<= 1) s += __shfl_xor(s, o);
  if (l == 0) {
    float p = 1.f / (1.f + expf(-(s + b_halt[0])));
    float cum = ws[OFF_CUM + b];
    float still = (cum < THRESH) ? 1.f : 0.f;
    bool nh = ((cum + p) >= THRESH) && (cum < THRESH);
    float wt = (nh ? (1.f - cum) : p) * still;
    ws[OFF_CUM + b] = cum + wt;
    ws[OFF_WT + b] = wt;
  }
}

// ---------------- ACT accumulate (R1) ----------------
__global__ __launch_bounds__(256) void k_acc(float* __restrict__ ws) {
  int i4 = blockIdx.x * 256 + threadIdx.x;
  int b = i4 >> 14;
  float wt = ws[OFF_WT + b];
  float4 z = ((const float4*)(ws + OFF_ZR))[i4];
  float4 a = ((float4*)(ws + OFF_AR))[i4];
  a.x += wt * z.x; a.y += wt * z.y; a.z += wt * z.z; a.w += wt * z.w;
  ((float4*)(ws + OFF_AR))[i4] = a;
  z = ((const float4*)(ws + OFF_ZI))[i4];
  a = ((float4*)(ws + OFF_AI))[i4];
  a.x += wt * z.x; a.y += wt * z.y; a.z += wt * z.z; a.w += wt * z.w;
  ((float4*)(ws + OFF_AI))[i4] = a;
}

// ---------------- output (R1) ----------------
__global__ __launch_bounds__(256) void k_out(const float* __restrict__ ws,
                                             float* __restrict__ out) {
  int i4 = blockIdx.x * 256 + threadIdx.x;
  ((float4*)out)[i4] = ((const float4*)(ws + OFF_AR))[i4];
  ((float4*)out)[i4 + BSD / 4] = ((const float4*)(ws + OFF_AI))[i4];
}

extern "C" void kernel_launch(void* const* d_in, const int* in_sizes, int n_in,
                              void* d_out, int out_size, void* d_ws, size_t ws_size,
                              hipStream_t stream) {
  (void)in_sizes; (void)n_in; (void)out_size; (void)ws_size;
  const float* x_real  = (const float*)d_in[0];
  const float* x_imag  = (const float*)d_in[1];
  const float* Wq_r    = (const float*)d_in[2];
  const float* Wq_i    = (const float*)d_in[3];
  const float* Wk_r    = (const float*)d_in[4];
  const float* Wk_i    = (const float*)d_in[5];
  const float* Wv_r    = (const float*)d_in[6];
  const float* Wv_i    = (const float*)d_in[7];
  const float* mod_bias = (const float*)d_in[8];
  const float* ln_scale = (const float*)d_in[9];
  const float* ln_shift = (const float*)d_in[10];
  const float* w_sal   = (const float*)d_in[11];
  const float* gru_Wih = (const float*)d_in[12];
  const float* gru_Whh = (const float*)d_in[13];
  const float* gru_bih = (const float*)d_in[14];
  const float* gru_bhh = (const float*)d_in[15];
  const float* bias_W  = (const float*)d_in[16];
  const float* bias_b  = (const float*)d_in[17];
  const float* w_halt  = (const float*)d_in[18];
  const float* b_halt  = (const float*)d_in[19];
  float* ws = (float*)d_ws;
  float* out = (float*)d_out;

  k_wprep<<<dim3(8, 8, 24), 256, 0, stream>>>(Wq_r, Wq_i, Wk_r, Wk_i, Wv_r, Wv_i, ws);
  k_init<<<512, 256, 0, stream>>>(x_real, x_imag, ws);
  k_gwp<<<32, 256, 0, stream>>>(ws + OFF_ZR, ws + OFF_ZI, ws + OFF_GWP);
  for (int step = 0; step < DEPTH; ++step) {
    const float* hold = ws + ((step & 1) ? OFF_H1 : OFF_H0);
    float* hnew = ws + ((step & 1) ? OFF_H0 : OFF_H1);
    k_gru<<<dim3(8, 8), 256, 0, stream>>>(ws + OFF_GWP, hold, hnew,
                                          gru_Wih, gru_Whh, gru_bih, gru_bhh);
    k_qkv<<<dim3(4, 8, 24), 256, 0, stream>>>(ws);
    k_attn<<<dim3(4, 32), 256, 0, stream>>>(ws);
    k_pv<<<dim3(8, 4, 32), 256, 0, stream>>>(ws);
    k_modln<<<M * B * S, 64, 0, stream>>>(ws, mod_bias, ln_scale, ln_shift);
    k_feat<<<256, 256, 0, stream>>>(ws);
    k_wsel<<<1, 256, 0, stream>>>(ws, hnew, bias_W, bias_b, w_sal);
    k_bcast<<<512, 256, 0, stream>>>(ws);
    k_gwp<<<32, 256, 0, stream>>>(ws + OFF_ZR, ws + OFF_ZI, ws + OFF_GWP);
    k_halt<<<1, 256, 0, stream>>>(ws, w_halt, b_halt);
    k_acc<<<512, 256, 0, stream>>>(ws);
  }
  k_out<<<512, 256, 0, stream>>>(ws, out);
}

// Round 8
// 4451.588 us; speedup vs baseline: 2.8188x; 1.0928x over previous
//
#include <hip/hip_runtime.h>
#include <math.h>

#define B 8
#define S 128
#define D 512
#define M 4
#define BS 1024
#define BSD 524288          // B*S*D
#define DEPTH 16
#define THRESH 0.9999f
#define EPS 1e-6f
#define SCALE 0.04419417382415922f   // D^-0.5

typedef float floatx4 __attribute__((ext_vector_type(4)));
typedef short s8v __attribute__((ext_vector_type(8)));
typedef unsigned short us4 __attribute__((ext_vector_type(4)));

__device__ __forceinline__ unsigned short f2bf(float f) {
  unsigned int u = __float_as_uint(f);
  u += 0x7FFFu + ((u >> 16) & 1u);          // round-to-nearest-even
  return (unsigned short)(u >> 16);
}
__device__ __forceinline__ float bf2f(unsigned short h) {
  return __uint_as_float((unsigned int)h << 16);
}

// ---------------- workspace layout (float-slot offsets) ----------------
#define OFF_ZR   0
#define OFF_ZI   (1*BSD)
#define OFF_AR   (2*BSD)
#define OFF_AI   (3*BSD)
#define OFF_OR   (4*BSD)            // [M][B][S][D] fp32 = 4*BSD
#define OFF_OI   (8*BSD)
#define OFF_FEAT (12*BSD)
#define OFF_GWP  (12*BSD + 65536)
#define OFF_H0   (12*BSD + 73728)
#define OFF_H1   (12*BSD + 77824)
#define OFF_CUM  (12*BSD + 81920)
#define OFF_W    (12*BSD + 81928)
#define OFF_WT   (12*BSD + 81960)
// bf16 annex (slots)
#define OFF_XH   (12*BSD + 90112)           // xcat hi [1024][1024] = 1 BSD
#define OFF_XL   (OFF_XH + 1*BSD)
#define OFF_WH   (OFF_XH + 2*BSD)           // 24 planes [512][512] hi = 6 BSD
#define OFF_WL   (OFF_XH + 8*BSD)
#define OFF_QCH  (OFF_XH + 14*BSD)          // Qcat hi [M][1024][1024] = 4 BSD
#define OFF_QCL  (OFF_XH + 18*BSD)
#define OFF_KCH  (OFF_XH + 22*BSD)
#define OFF_KCL  (OFF_XH + 26*BSD)
#define OFF_VTH  (OFF_XH + 30*BSD)          // Vt hi [2ri][M][512][1024] = 4 BSD
#define OFF_VTL  (OFF_XH + 34*BSD)
#define OFF_PH   (OFF_XH + 38*BSD)          // P hi [32][128][128] = 262144 slots
#define OFF_PL   (OFF_PH + 262144)
// end = 50*BSD + 614400 + 90112... = 26,828,800 slots = 107.3 MB (== R6 proven)

// ---------------- init: fp32 carry + bf16 hi/lo Xcat ----------------
__global__ __launch_bounds__(256) void k_init(const float* __restrict__ xr,
                                              const float* __restrict__ xi,
                                              float* __restrict__ ws) {
  unsigned short* xh = (unsigned short*)(ws + OFF_XH);
  unsigned short* xl = (unsigned short*)(ws + OFF_XL);
  int i4 = blockIdx.x * 256 + threadIdx.x;      // BSD/4
  float4 a = ((const float4*)xr)[i4];
  float4 b = ((const float4*)xi)[i4];
  ((float4*)(ws + OFF_ZR))[i4] = a;
  ((float4*)(ws + OFF_ZI))[i4] = b;
  float4 z = {0.f, 0.f, 0.f, 0.f};
  ((float4*)(ws + OFF_AR))[i4] = z;
  ((float4*)(ws + OFF_AI))[i4] = z;
  int row = i4 >> 7;
  int d4 = (i4 & 127) * 4;
  float av[4] = {a.x, a.y, a.z, a.w}, bv[4] = {b.x, b.y, b.z, b.w};
  us4 hh, hl;
#pragma unroll
  for (int j = 0; j < 4; ++j) {
    unsigned short h = f2bf(av[j]); hh[j] = h; hl[j] = f2bf(av[j] - bf2f(h));
  }
  *(us4*)(xh + (size_t)row * 1024 + d4) = hh;
  *(us4*)(xl + (size_t)row * 1024 + d4) = hl;
#pragma unroll
  for (int j = 0; j < 4; ++j) {
    unsigned short h = f2bf(bv[j]); hh[j] = h; hl[j] = f2bf(bv[j] - bf2f(h));
  }
  *(us4*)(xh + (size_t)row * 1024 + 512 + d4) = hh;
  *(us4*)(xl + (size_t)row * 1024 + 512 + d4) = hl;
  if (i4 < (B * D) / 4) {
    ((float4*)(ws + OFF_H0))[i4] = z;
    ((float4*)(ws + OFF_H1))[i4] = z;
  }
  if (i4 < B) ws[OFF_CUM + i4] = 0.f;
}

// ---------------- weight prep (R6, proven) ----------------
__global__ __launch_bounds__(256) void k_wprep(const float* __restrict__ Wqr,
                                               const float* __restrict__ Wqi,
                                               const float* __restrict__ Wkr,
                                               const float* __restrict__ Wki,
                                               const float* __restrict__ Wvr,
                                               const float* __restrict__ Wvi,
                                               float* __restrict__ ws) {
  __shared__ float lt[64][65];
  unsigned short* wh = (unsigned short*)(ws + OFF_WH);
  unsigned short* wl = (unsigned short*)(ws + OFF_WL);
  int z = blockIdx.z, m = z / 6, idx = z % 6;
  const float* Wsrc;
  switch (idx) {
    case 0:  Wsrc = Wqr; break;
    case 1:  Wsrc = Wqi; break;
    case 2:  Wsrc = Wkr; break;
    case 3:  Wsrc = Wki; break;
    case 4:  Wsrc = Wvr; break;
    default: Wsrc = Wvi; break;
  }
  Wsrc += (size_t)m * D * D;
  int k0 = blockIdx.x * 64, n0 = blockIdx.y * 64;
  int tx = threadIdx.x & 63, ty = threadIdx.x >> 6;
#pragma unroll
  for (int i = 0; i < 16; ++i) {
    int kl = ty + i * 4;
    lt[kl][tx] = Wsrc[(size_t)(k0 + kl) * D + n0 + tx];
  }
  __syncthreads();
  unsigned short* whp = wh + (size_t)z * 262144;
  unsigned short* wlp = wl + (size_t)z * 262144;
#pragma unroll
  for (int i = 0; i < 16; ++i) {
    int nl = ty + i * 4;
    float v = lt[tx][nl];
    unsigned short h = f2bf(v);
    whp[(size_t)(n0 + nl) * 512 + k0 + tx] = h;
    wlp[(size_t)(n0 + nl) * 512 + k0 + tx] = f2bf(v - bf2f(h));
  }
}

// ---------------- gwp (R1) ----------------
__global__ __launch_bounds__(256) void k_gwp(const float* __restrict__ zr,
                                             const float* __restrict__ zi,
                                             float* __restrict__ gwp) {
  int idx = blockIdx.x * 256 + threadIdx.x;
  int b = idx >> 10;
  int f = idx & 1023;
  const float* src = (f < D) ? (zr + b * S * D + f) : (zi + b * S * D + (f - D));
  float s = 0.f;
#pragma unroll 8
  for (int ss = 0; ss < S; ++ss) s += src[ss * D];
  gwp[idx] = s * (1.0f / S);
}

// ---------------- GRU: k-split reduction GEMM (R7, proven) ----------------
__global__ __launch_bounds__(256) void k_gru(const float* __restrict__ gwp,
                                             const float* __restrict__ hold,
                                             float* __restrict__ hnew,
                                             const float* __restrict__ Wih,
                                             const float* __restrict__ Whh,
                                             const float* __restrict__ bih,
                                             const float* __restrict__ bhh) {
  __shared__ float xbuf[1024];
  __shared__ float hbuf[512];
  __shared__ float red[4][64][4];
  int b = blockIdx.y;
  int t = threadIdx.x;
  int td = t & 63, ks = t >> 6;
  int c0 = blockIdx.x * 64;
  for (int f = t; f < 1024; f += 256) xbuf[f] = gwp[b * 1024 + f];
  for (int d2 = t; d2 < 512; d2 += 256) hbuf[d2] = hold[b * 512 + d2];
  __syncthreads();
  float accR = 0.f, accZ = 0.f, accXn = 0.f, accHn = 0.f;
  int kbeg = ks * 384, kend = kbeg + 384;
#pragma unroll 4
  for (int kk = kbeg; kk < kend; ++kk) {
    bool ih = kk < 1024;
    float x = ih ? xbuf[kk] : hbuf[kk - 1024];
    const float* base = ih ? (Wih + (size_t)kk * 1536) : (Whh + (size_t)(kk - 1024) * 1536);
    float wr = base[c0 + td];
    float wz = base[512 + c0 + td];
    float wn = base[1024 + c0 + td];
    accR += x * wr;
    accZ += x * wz;
    if (ih) accXn += x * wn; else accHn += x * wn;
  }
  red[ks][td][0] = accR;
  red[ks][td][1] = accZ;
  red[ks][td][2] = accXn;
  red[ks][td][3] = accHn;
  __syncthreads();
  if (t < 64) {
    int c = c0 + t;
    float r_ = 0.f, z_ = 0.f, xn = 0.f, hn = 0.f;
#pragma unroll
    for (int s = 0; s < 4; ++s) {
      r_ += red[s][t][0]; z_ += red[s][t][1]; xn += red[s][t][2]; hn += red[s][t][3];
    }
    r_ += bih[c] + bhh[c];
    z_ += bih[512 + c] + bhh[512 + c];
    xn += bih[1024 + c];
    hn += bhh[1024 + c];
    float r = 1.f / (1.f + expf(-r_));
    float z = 1.f / (1.f + expf(-z_));
    float n = tanhf(xn + r * hn);
    hnew[b * 512 + c] = (1.f - z) * n + z * hbuf[c];
  }
}

// ---------------- QKV: bf16x3 MFMA; Q/K -> Qcat/Kcat hi/lo, V -> Vt hi/lo ----------------
// grid (4, 8, 24), 256 thr. 128x128 tile, BK=32.
// QK mode (w6<4): A=xcat rows(bs), B=wct rows(n) -> D[bs][n].
// V  mode (w6>=4): A=wct rows(e) (+sign), B=xcat rows(bs) -> D[e][bs] = V^T.
__global__ __launch_bounds__(256) void k_qkv(float* __restrict__ ws) {
  __shared__ __align__(16) unsigned short Ah[128 * 32], Al[128 * 32];
  __shared__ __align__(16) unsigned short Bh[128 * 32], Bl[128 * 32];
  const unsigned short* xh = (const unsigned short*)(ws + OFF_XH);
  const unsigned short* xl = (const unsigned short*)(ws + OFF_XL);
  const unsigned short* wh = (const unsigned short*)(ws + OFF_WH);
  const unsigned short* wl = (const unsigned short*)(ws + OFF_WL);
  int g = blockIdx.z, m = g / 6, w6 = g % 6;
  bool qk = (w6 < 4);
  int pair = (w6 >> 1) * 2;
  int p1 = m * 6 + pair + (w6 & 1);
  int p2 = m * 6 + pair + ((w6 & 1) ^ 1);
  unsigned int xmask = (w6 & 1) ? 0u : 0x80008000u;
  const unsigned short* PH1 = wh + (size_t)p1 * 262144;
  const unsigned short* PL1 = wl + (size_t)p1 * 262144;
  const unsigned short* PH2 = wh + (size_t)p2 * 262144;
  const unsigned short* PL2 = wl + (size_t)p2 * 262144;

  int row0 = qk ? blockIdx.y * 128 : blockIdx.x * 128;   // QK: bs(1024,y) ; V: e(512,x)
  int col0 = qk ? blockIdx.x * 128 : blockIdx.y * 128;   // QK: n(512,x)  ; V: bs(1024,y)
  int wb = qk ? col0 : row0;                              // wct tile base rows
  int xb = qk ? row0 : col0;                              // xcat tile base rows
  int t = threadIdx.x, lane = t & 63, w = t >> 6;
  int wr = w >> 1, wc = w & 1;
  int q = lane >> 4, r = lane & 15;
  int srow = t >> 2;
  int skoff = (t & 3) * 8;
  size_t wrow1 = (size_t)(wb + srow) * 512 + skoff;
  size_t wrow2 = (size_t)(wb + 64 + srow) * 512 + skoff;
  size_t xrow1 = (size_t)(xb + srow) * 1024 + skoff;
  size_t xrow2 = (size_t)(xb + 64 + srow) * 1024 + skoff;

  floatx4 acc[4][4];
#pragma unroll
  for (int i = 0; i < 4; ++i)
#pragma unroll
    for (int j = 0; j < 4; ++j) acc[i][j] = (floatx4){0.f, 0.f, 0.f, 0.f};

  for (int k0 = 0; k0 < 1024; k0 += 32) {
    const unsigned short *WgH, *WgL;
    unsigned int xm;
    int kk = k0;
    if (k0 < 512) { WgH = PH1; WgL = PL1; xm = 0u; }
    else          { WgH = PH2; WgL = PL2; xm = xmask; kk = k0 - 512; }
    uint4 w0h = *(const uint4*)(WgH + wrow1 + kk);
    uint4 w1h = *(const uint4*)(WgH + wrow2 + kk);
    uint4 w0l = *(const uint4*)(WgL + wrow1 + kk);
    uint4 w1l = *(const uint4*)(WgL + wrow2 + kk);
    w0h.x ^= xm; w0h.y ^= xm; w0h.z ^= xm; w0h.w ^= xm;
    w1h.x ^= xm; w1h.y ^= xm; w1h.z ^= xm; w1h.w ^= xm;
    w0l.x ^= xm; w0l.y ^= xm; w0l.z ^= xm; w0l.w ^= xm;
    w1l.x ^= xm; w1l.y ^= xm; w1l.z ^= xm; w1l.w ^= xm;
    uint4 x0h = *(const uint4*)(xh + xrow1 + k0);
    uint4 x1h = *(const uint4*)(xh + xrow2 + k0);
    uint4 x0l = *(const uint4*)(xl + xrow1 + k0);
    uint4 x1l = *(const uint4*)(xl + xrow2 + k0);
    if (qk) {
      *(uint4*)(Ah + srow * 32 + skoff) = x0h;
      *(uint4*)(Ah + (64 + srow) * 32 + skoff) = x1h;
      *(uint4*)(Al + srow * 32 + skoff) = x0l;
      *(uint4*)(Al + (64 + srow) * 32 + skoff) = x1l;
      *(uint4*)(Bh + srow * 32 + skoff) = w0h;
      *(uint4*)(Bh + (64 + srow) * 32 + skoff) = w1h;
      *(uint4*)(Bl + srow * 32 + skoff) = w0l;
      *(uint4*)(Bl + (64 + srow) * 32 + skoff) = w1l;
    } else {
      *(uint4*)(Ah + srow * 32 + skoff) = w0h;
      *(uint4*)(Ah + (64 + srow) * 32 + skoff) = w1h;
      *(uint4*)(Al + srow * 32 + skoff) = w0l;
      *(uint4*)(Al + (64 + srow) * 32 + skoff) = w1l;
      *(uint4*)(Bh + srow * 32 + skoff) = x0h;
      *(uint4*)(Bh + (64 + srow) * 32 + skoff) = x1h;
      *(uint4*)(Bl + srow * 32 + skoff) = x0l;
      *(uint4*)(Bl + (64 + srow) * 32 + skoff) = x1l;
    }
    __syncthreads();
    s8v ah[4], al[4], bh[4], bl[4];
#pragma unroll
    for (int i = 0; i < 4; ++i) {
      int ro = (wr * 64 + i * 16 + r) * 32 + q * 8;
      ah[i] = *(const s8v*)((const short*)Ah + ro);
      al[i] = *(const s8v*)((const short*)Al + ro);
    }
#pragma unroll
    for (int j = 0; j < 4; ++j) {
      int ro = (wc * 64 + j * 16 + r) * 32 + q * 8;
      bh[j] = *(const s8v*)((const short*)Bh + ro);
      bl[j] = *(const s8v*)((const short*)Bl + ro);
    }
#pragma unroll
    for (int i = 0; i < 4; ++i)
#pragma unroll
      for (int j = 0; j < 4; ++j) {
        acc[i][j] = __builtin_amdgcn_mfma_f32_16x16x32_bf16(ah[i], bh[j], acc[i][j], 0, 0, 0);
        acc[i][j] = __builtin_amdgcn_mfma_f32_16x16x32_bf16(ah[i], bl[j], acc[i][j], 0, 0, 0);
        acc[i][j] = __builtin_amdgcn_mfma_f32_16x16x32_bf16(al[i], bh[j], acc[i][j], 0, 0, 0);
      }
    __syncthreads();
  }
  // epilogue: write hi/lo bf16
  unsigned short *dh, *dl;
  size_t base;
  int half = 0;
  if (qk) {
    if (w6 < 2) { dh = (unsigned short*)(ws + OFF_QCH); dl = (unsigned short*)(ws + OFF_QCL); }
    else        { dh = (unsigned short*)(ws + OFF_KCH); dl = (unsigned short*)(ws + OFF_KCL); }
    half = (w6 & 1) * 512;
    base = (size_t)m * 1024 * 1024;
  } else {
    dh = (unsigned short*)(ws + OFF_VTH);
    dl = (unsigned short*)(ws + OFF_VTL);
    base = (size_t)((w6 & 1) * 4 + m) * 512 * 1024;
  }
#pragma unroll
  for (int i = 0; i < 4; ++i)
#pragma unroll
    for (int j = 0; j < 4; ++j) {
      int rowb = row0 + wr * 64 + i * 16 + q * 4;
      int colb = col0 + wc * 64 + j * 16 + r;
#pragma unroll
      for (int reg = 0; reg < 4; ++reg) {
        float v = acc[i][j][reg];
        unsigned short h = f2bf(v);
        size_t idx = base + (size_t)(rowb + reg) * 1024 + half + colb;
        dh[idx] = h;
        dl[idx] = f2bf(v - bf2f(h));
      }
    }
}

// ---------------- attn: scores (bf16x3 MFMA, K=1024) + in-register softmax -> P hi/lo ----------------
// grid 32 (mb = m*8+b), 256 thr. Full 128x128 tile.
__global__ __launch_bounds__(256) void k_attn(float* __restrict__ ws) {
  __shared__ __align__(16) unsigned short Ah[128 * 32], Al[128 * 32];
  __shared__ __align__(16) unsigned short Bh[128 * 32], Bl[128 * 32];
  __shared__ float rmax[128][2];
  __shared__ float rsum[128][2];
  const unsigned short* qch = (const unsigned short*)(ws + OFF_QCH);
  const unsigned short* qcl = (const unsigned short*)(ws + OFF_QCL);
  const unsigned short* kch = (const unsigned short*)(ws + OFF_KCH);
  const unsigned short* kcl = (const unsigned short*)(ws + OFF_KCL);
  unsigned short* ph = (unsigned short*)(ws + OFF_PH);
  unsigned short* pl = (unsigned short*)(ws + OFF_PL);
  int mb = blockIdx.x;
  size_t gbase = (size_t)mb * 128 * 1024;
  int t = threadIdx.x, lane = t & 63, w = t >> 6;
  int wr = w >> 1, wc = w & 1;
  int q = lane >> 4, r = lane & 15;
  int srow = t >> 2;
  int skoff = (t & 3) * 8;
  size_t arow1 = gbase + (size_t)srow * 1024 + skoff;
  size_t arow2 = gbase + (size_t)(64 + srow) * 1024 + skoff;

  floatx4 acc[4][4];
#pragma unroll
  for (int i = 0; i < 4; ++i)
#pragma unroll
    for (int j = 0; j < 4; ++j) acc[i][j] = (floatx4){0.f, 0.f, 0.f, 0.f};

  for (int k0 = 0; k0 < 1024; k0 += 32) {
    uint4 a0h = *(const uint4*)(qch + arow1 + k0);
    uint4 a1h = *(const uint4*)(qch + arow2 + k0);
    uint4 a0l = *(const uint4*)(qcl + arow1 + k0);
    uint4 a1l = *(const uint4*)(qcl + arow2 + k0);
    uint4 b0h = *(const uint4*)(kch + arow1 + k0);
    uint4 b1h = *(const uint4*)(kch + arow2 + k0);
    uint4 b0l = *(const uint4*)(kcl + arow1 + k0);
    uint4 b1l = *(const uint4*)(kcl + arow2 + k0);
    *(uint4*)(Ah + srow * 32 + skoff) = a0h;
    *(uint4*)(Ah + (64 + srow) * 32 + skoff) = a1h;
    *(uint4*)(Al + srow * 32 + skoff) = a0l;
    *(uint4*)(Al + (64 + srow) * 32 + skoff) = a1l;
    *(uint4*)(Bh + srow * 32 + skoff) = b0h;
    *(uint4*)(Bh + (64 + srow) * 32 + skoff) = b1h;
    *(uint4*)(Bl + srow * 32 + skoff) = b0l;
    *(uint4*)(Bl + (64 + srow) * 32 + skoff) = b1l;
    __syncthreads();
    s8v ah[4], al[4], bh[4], bl[4];
#pragma unroll
    for (int i = 0; i < 4; ++i) {
      int ro = (wr * 64 + i * 16 + r) * 32 + q * 8;
      ah[i] = *(const s8v*)((const short*)Ah + ro);
      al[i] = *(const s8v*)((const short*)Al + ro);
    }
#pragma unroll
    for (int j = 0; j < 4; ++j) {
      int ro = (wc * 64 + j * 16 + r) * 32 + q * 8;
      bh[j] = *(const s8v*)((const short*)Bh + ro);
      bl[j] = *(const s8v*)((const short*)Bl + ro);
    }
#pragma unroll
    for (int i = 0; i < 4; ++i)
#pragma unroll
      for (int j = 0; j < 4; ++j) {
        acc[i][j] = __builtin_amdgcn_mfma_f32_16x16x32_bf16(ah[i], bh[j], acc[i][j], 0, 0, 0);
        acc[i][j] = __builtin_amdgcn_mfma_f32_16x16x32_bf16(ah[i], bl[j], acc[i][j], 0, 0, 0);
        acc[i][j] = __builtin_amdgcn_mfma_f32_16x16x32_bf16(al[i], bh[j], acc[i][j], 0, 0, 0);
      }
    __syncthreads();
  }
  // scale + wave-local row max (across 16 lanes sharing q), rows = wr*64+i*16+q*4+reg
#pragma unroll
  for (int i = 0; i < 4; ++i)
#pragma unroll
    for (int j = 0; j < 4; ++j)
#pragma unroll
      for (int reg = 0; reg < 4; ++reg) acc[i][j][reg] *= SCALE;
#pragma unroll
  for (int i = 0; i < 4; ++i)
#pragma unroll
    for (int reg = 0; reg < 4; ++reg) {
      float mx = fmaxf(fmaxf(acc[i][0][reg], acc[i][1][reg]),
                       fmaxf(acc[i][2][reg], acc[i][3][reg]));
      for (int o = 1; o < 16; o <<= 1) mx = fmaxf(mx, __shfl_xor(mx, o));
      if (r == 0) rmax[wr * 64 + i * 16 + q * 4 + reg][wc] = mx;
    }
  __syncthreads();
#pragma unroll
  for (int i = 0; i < 4; ++i)
#pragma unroll
    for (int reg = 0; reg < 4; ++reg) {
      int row = wr * 64 + i * 16 + q * 4 + reg;
      float gmx = fmaxf(rmax[row][0], rmax[row][1]);
      float sm = 0.f;
#pragma unroll
      for (int j = 0; j < 4; ++j) {
        float e = __expf(acc[i][j][reg] - gmx);
        acc[i][j][reg] = e;
        sm += e;
      }
      for (int o = 1; o < 16; o <<= 1) sm += __shfl_xor(sm, o);
      if (r == 0) rsum[row][wc] = sm;
    }
  __syncthreads();
#pragma unroll
  for (int i = 0; i < 4; ++i)
#pragma unroll
    for (int reg = 0; reg < 4; ++reg) {
      int row = wr * 64 + i * 16 + q * 4 + reg;
      float inv = 1.f / (rsum[row][0] + rsum[row][1]);
      size_t rb = (size_t)(mb * 128 + row) * 128;
#pragma unroll
      for (int j = 0; j < 4; ++j) {
        float p = acc[i][j][reg] * inv;
        unsigned short h = f2bf(p);
        size_t idx = rb + wc * 64 + j * 16 + r;
        ph[idx] = h;
        pl[idx] = f2bf(p - bf2f(h));
      }
    }
}

// ---------------- PV: O = P @ Vt^T (bf16x3 MFMA, K=128), fp32 out ----------------
// grid (4 e-tiles, 32 mb), 256 thr. Tile 128s x 128e.
__global__ __launch_bounds__(256) void k_pv(float* __restrict__ ws) {
  __shared__ __align__(16) unsigned short Ph_[128 * 32], Pl_[128 * 32];
  __shared__ __align__(16) unsigned short VrH[128 * 32], VrL[128 * 32];
  __shared__ __align__(16) unsigned short ViH[128 * 32], ViL[128 * 32];
  const unsigned short* ph = (const unsigned short*)(ws + OFF_PH);
  const unsigned short* pl = (const unsigned short*)(ws + OFF_PL);
  const unsigned short* vth = (const unsigned short*)(ws + OFF_VTH);
  const unsigned short* vtl = (const unsigned short*)(ws + OFF_VTL);
  int mb = blockIdx.y, m = mb >> 3, b = mb & 7;
  int col0 = blockIdx.x * 128;                       // e tile
  int t = threadIdx.x, lane = t & 63, w = t >> 6;
  int wr = w >> 1, wc = w & 1;
  int q = lane >> 4, r = lane & 15;
  int srow = t >> 2;
  int skoff = (t & 3) * 8;
  size_t prow1 = (size_t)(mb * 128 + srow) * 128 + skoff;
  size_t prow2 = (size_t)(mb * 128 + 64 + srow) * 128 + skoff;
  size_t vbr1 = ((size_t)(m * 512) + col0 + srow) * 1024 + b * 128 + skoff;
  size_t vbr2 = ((size_t)(m * 512) + col0 + 64 + srow) * 1024 + b * 128 + skoff;
  size_t vplane_i = (size_t)4 * 512 * 1024;          // ri=1 offset in rows*1024

  floatx4 accR[4][4], accI[4][4];
#pragma unroll
  for (int i = 0; i < 4; ++i)
#pragma unroll
    for (int j = 0; j < 4; ++j) {
      accR[i][j] = (floatx4){0.f, 0.f, 0.f, 0.f};
      accI[i][j] = (floatx4){0.f, 0.f, 0.f, 0.f};
    }

  for (int k0 = 0; k0 < 128; k0 += 32) {
    *(uint4*)(Ph_ + srow * 32 + skoff) = *(const uint4*)(ph + prow1 + k0);
    *(uint4*)(Ph_ + (64 + srow) * 32 + skoff) = *(const uint4*)(ph + prow2 + k0);
    *(uint4*)(Pl_ + srow * 32 + skoff) = *(const uint4*)(pl + prow1 + k0);
    *(uint4*)(Pl_ + (64 + srow) * 32 + skoff) = *(const uint4*)(pl + prow2 + k0);
    *(uint4*)(VrH + srow * 32 + skoff) = *(const uint4*)(vth + vbr1 + k0);
    *(uint4*)(VrH + (64 + srow) * 32 + skoff) = *(const uint4*)(vth + vbr2 + k0);
    *(uint4*)(VrL + srow * 32 + skoff) = *(const uint4*)(vtl + vbr1 + k0);
    *(uint4*)(VrL + (64 + srow) * 32 + skoff) = *(const uint4*)(vtl + vbr2 + k0);
    *(uint4*)(ViH + srow * 32 + skoff) = *(const uint4*)(vth + vplane_i + vbr1 + k0);
    *(uint4*)(ViH + (64 + srow) * 32 + skoff) = *(const uint4*)(vth + vplane_i + vbr2 + k0);
    *(uint4*)(ViL + srow * 32 + skoff) = *(const uint4*)(vtl + vplane_i + vbr1 + k0);
    *(uint4*)(ViL + (64 + srow) * 32 + skoff) = *(const uint4*)(vtl + vplane_i + vbr2 + k0);
    __syncthreads();
    s8v ah[4], al[4];
#pragma unroll
    for (int i = 0; i < 4; ++i) {
      int ro = (wr * 64 + i * 16 + r) * 32 + q * 8;
      ah[i] = *(const s8v*)((const short*)Ph_ + ro);
      al[i] = *(const s8v*)((const short*)Pl_ + ro);
    }
#pragma unroll
    for (int j = 0; j < 4; ++j) {
      int ro = (wc * 64 + j * 16 + r) * 32 + q * 8;
      s8v vrh = *(const s8v*)((const short*)VrH + ro);
      s8v vrl = *(const s8v*)((const short*)VrL + ro);
      s8v vih = *(const s8v*)((const short*)ViH + ro);
      s8v vil = *(const s8v*)((const short*)ViL + ro);
#pragma unroll
      for (int i = 0; i < 4; ++i) {
        accR[i][j] = __builtin_amdgcn_mfma_f32_16x16x32_bf16(ah[i], vrh, accR[i][j], 0, 0, 0);
        accR[i][j] = __builtin_amdgcn_mfma_f32_16x16x32_bf16(ah[i], vrl, accR[i][j], 0, 0, 0);
        accR[i][j] = __builtin_amdgcn_mfma_f32_16x16x32_bf16(al[i], vrh, accR[i][j], 0, 0, 0);
        accI[i][j] = __builtin_amdgcn_mfma_f32_16x16x32_bf16(ah[i], vih, accI[i][j], 0, 0, 0);
        accI[i][j] = __builtin_amdgcn_mfma_f32_16x16x32_bf16(ah[i], vil, accI[i][j], 0, 0, 0);
        accI[i][j] = __builtin_amdgcn_mfma_f32_16x16x32_bf16(al[i], vih, accI[i][j], 0, 0, 0);
      }
    }
    __syncthreads();
  }
  float* orp = ws + OFF_OR + (size_t)mb * 128 * 512;
  float* oip = ws + OFF_OI + (size_t)mb * 128 * 512;
#pragma unroll
  for (int i = 0; i < 4; ++i)
#pragma unroll
    for (int j = 0; j < 4; ++j) {
      int rowb = wr * 64 + i * 16 + q * 4;
      int colb = col0 + wc * 64 + j * 16 + r;
#pragma unroll
      for (int reg = 0; reg < 4; ++reg) {
        orp[(size_t)(rowb + reg) * 512 + colb] = accR[i][j][reg];
        oip[(size_t)(rowb + reg) * 512 + colb] = accI[i][j][reg];
      }
    }
}

// ---------------- ModReLU + ComplexLayerNorm (R1) ----------------
__global__ __launch_bounds__(64) void k_modln(float* __restrict__ ws,
                                              const float* __restrict__ mod_bias,
                                              const float* __restrict__ ln_scale,
                                              const float* __restrict__ ln_shift) {
  int blk = blockIdx.x;
  int m = blk / (B * S);
  int t = threadIdx.x;
  float* orp = ws + OFF_OR + (size_t)blk * D;
  float* oip = ws + OFF_OI + (size_t)blk * D;
  float orv[2][4], oiv[2][4], magv[2][4];
  float sum = 0.f, sumsq = 0.f;
#pragma unroll
  for (int k = 0; k < 2; ++k) {
    float4 a = *(const float4*)(orp + t * 4 + k * 256);
    float4 c = *(const float4*)(oip + t * 4 + k * 256);
    float av[4] = {a.x, a.y, a.z, a.w}, cv[4] = {c.x, c.y, c.z, c.w};
#pragma unroll
    for (int j = 0; j < 4; ++j) {
      int e = t * 4 + k * 256 + j;
      float o_r = av[j], o_i = cv[j];
      float mag = sqrtf(o_r * o_r + o_i * o_i) + EPS;
      float g = fmaxf(mag + mod_bias[m * D + e], 0.f) / mag;
      o_r *= g; o_i *= g;
      orv[k][j] = o_r; oiv[k][j] = o_i;
      float mag2 = sqrtf(o_r * o_r + o_i * o_i) + EPS;
      magv[k][j] = mag2;
      sum += mag2;
      sumsq += mag2 * mag2;
    }
  }
  for (int o = 1; o < 64; o <<= 1) {
    sum += __shfl_xor(sum, o);
    sumsq += __shfl_xor(sumsq, o);
  }
  float mu = sum * (1.f / D);
  float var = (sumsq - (float)D * mu * mu) * (1.f / (D - 1));
  float inv = 1.f / sqrtf(var + EPS);
#pragma unroll
  for (int k = 0; k < 2; ++k) {
#pragma unroll
    for (int j = 0; j < 4; ++j) {
      int e = t * 4 + k * 256 + j;
      float nm = (magv[k][j] - mu) * inv * ln_scale[m * D + e] + ln_shift[m * D + e];
      float hyp = magv[k][j] - EPS;
      float cp, sp;
      if (hyp > 0.f) { cp = orv[k][j] / hyp; sp = oiv[k][j] / hyp; }
      else           { cp = 1.f;             sp = 0.f; }
      orv[k][j] = nm * cp;
      oiv[k][j] = nm * sp;
    }
    float4 a = {orv[k][0], orv[k][1], orv[k][2], orv[k][3]};
    float4 c = {oiv[k][0], oiv[k][1], oiv[k][2], oiv[k][3]};
    *(float4*)(orp + t * 4 + k * 256) = a;
    *(float4*)(oip + t * 4 + k * 256) = c;
  }
}

// ---------------- feat (R1) ----------------
__global__ __launch_bounds__(256) void k_feat(float* __restrict__ ws) {
  int idx = blockIdx.x * 256 + threadIdx.x;
  int mb = idx >> 10;
  int f = idx & 1023;
  const float* src = ws + ((f < D) ? OFF_OR : OFF_OI) + mb * S * D + ((f < D) ? f : f - D);
  float s = 0.f;
#pragma unroll 8
  for (int ss = 0; ss < S; ++ss) s += src[ss * D];
  ws[OFF_FEAT + idx] = s * (1.0f / S);
}

// ---------------- wsel (R1) ----------------
__global__ __launch_bounds__(256) void k_wsel(float* __restrict__ ws,
                                              const float* __restrict__ hnew,
                                              const float* __restrict__ bias_W,
                                              const float* __restrict__ bias_b,
                                              const float* __restrict__ w_sal) {
  __shared__ float mb_s[B][M];
  __shared__ float sal_s[M][B];
  int t = threadIdx.x;
  int p = t >> 3, l = t & 7;
  {
    int b = p >> 2, m = p & 3;
    float s = 0.f;
    for (int d2 = l; d2 < D; d2 += 8) s += hnew[b * D + d2] * bias_W[d2 * M + m];
    for (int o = 1; o < 8; o <<= 1) s += __shfl_xor(s, o);
    if (l == 0) mb_s[b][m] = s + bias_b[m];
  }
  {
    int m = p >> 3, b = p & 7;
    float s = 0.f;
    for (int f = l; f < 2 * D; f += 8) s += ws[OFF_FEAT + (m * B + b) * 2 * D + f] * w_sal[m * 2 * D + f];
    for (int o = 1; o < 8; o <<= 1) s += __shfl_xor(s, o);
    if (l == 0) sal_s[m][b] = s;
  }
  __syncthreads();
  if (t < B) {
    int b = t;
    float lg[M], mx = -1e30f;
#pragma unroll
    for (int m = 0; m < M; ++m) { lg[m] = sal_s[m][b] + mb_s[b][m]; mx = fmaxf(mx, lg[m]); }
    float sm = 0.f;
#pragma unroll
    for (int m = 0; m < M; ++m) { lg[m] = expf(lg[m] - mx); sm += lg[m]; }
    float inv = 1.f / sm;
#pragma unroll
    for (int m = 0; m < M; ++m) ws[OFF_W + m * B + b] = lg[m] * inv;
  }
}

// ---------------- bcast (R1 fp32) + bf16 hi/lo Xcat refresh ----------------
__global__ __launch_bounds__(256) void k_bcast(float* __restrict__ ws) {
  unsigned short* xh = (unsigned short*)(ws + OFF_XH);
  unsigned short* xl = (unsigned short*)(ws + OFF_XL);
  int i4 = blockIdx.x * 256 + threadIdx.x;
  int b = i4 >> 14;
  float w0 = ws[OFF_W + 0 * B + b], w1 = ws[OFF_W + 1 * B + b];
  float w2 = ws[OFF_W + 2 * B + b], w3 = ws[OFF_W + 3 * B + b];
  const float4* mr = (const float4*)(ws + OFF_OR);
  const float4* mi = (const float4*)(ws + OFF_OI);
  const int MS = BSD / 4;
  int row = i4 >> 7;
  int d4 = (i4 & 127) * 4;
  float4 r0 = mr[i4], r1 = mr[i4 + MS], r2 = mr[i4 + 2 * MS], r3 = mr[i4 + 3 * MS];
  float gv[4];
  gv[0] = w0 * r0.x + w1 * r1.x + w2 * r2.x + w3 * r3.x;
  gv[1] = w0 * r0.y + w1 * r1.y + w2 * r2.y + w3 * r3.y;
  gv[2] = w0 * r0.z + w1 * r1.z + w2 * r2.z + w3 * r3.z;
  gv[3] = w0 * r0.w + w1 * r1.w + w2 * r2.w + w3 * r3.w;
  ((float4*)(ws + OFF_ZR))[i4] = (float4){gv[0], gv[1], gv[2], gv[3]};
  us4 hh, hl;
#pragma unroll
  for (int j = 0; j < 4; ++j) {
    unsigned short h = f2bf(gv[j]); hh[j] = h; hl[j] = f2bf(gv[j] - bf2f(h));
  }
  *(us4*)(xh + (size_t)row * 1024 + d4) = hh;
  *(us4*)(xl + (size_t)row * 1024 + d4) = hl;
  float4 s0 = mi[i4], s1 = mi[i4 + MS], s2 = mi[i4 + 2 * MS], s3 = mi[i4 + 3 * MS];
  gv[0] = w0 * s0.x + w1 * s1.x + w2 * s2.x + w3 * s3.x;
  gv[1] = w0 * s0.y + w1 * s1.y + w2 * s2.y + w3 * s3.y;
  gv[2] = w0 * s0.z + w1 * s1.z + w2 * s2.z + w3 * s3.z;
  gv[3] = w0 * s0.w + w1 * s1.w + w2 * s2.w + w3 * s3.w;
  ((float4*)(ws + OFF_ZI))[i4] = (float4){gv[0], gv[1], gv[2], gv[3]};
#pragma unroll
  for (int j = 0; j < 4; ++j) {
    unsigned short h = f2bf(gv[j]); hh[j] = h; hl[j] = f2bf(gv[j] - bf2f(h));
  }
  *(us4*)(xh + (size_t)row * 1024 + 512 + d4) = hh;
  *(us4*)(xl + (size_t)row * 1024 + 512 + d4) = hl;
}

// ---------------- halting (R1) ----------------
__global__ __launch_bounds__(256) void k_halt(float* __restrict__ ws,
                                              const float* __restrict__ w_halt,
                                              const float* __restrict__ b_halt) {
  int t = threadIdx.x;
  int b = t >> 5, l = t & 31;
  float s = 0.f;
  for (int f = l; f < 2 * D; f += 32) s += ws[OFF_GWP + b * 2 * D + f] * w_halt[f];
  for (int o = 1; o < 32; o <<= 1) s += __shfl_xor(s, o);
  if (l == 0) {
    float p = 1.f / (1.f + expf(-(s + b_halt[0])));
    float cum = ws[OFF_CUM + b];
    float still = (cum < THRESH) ? 1.f : 0.f;
    bool nh = ((cum + p) >= THRESH) && (cum < THRESH);
    float wt = (nh ? (1.f - cum) : p) * still;
    ws[OFF_CUM + b] = cum + wt;
    ws[OFF_WT + b] = wt;
  }
}

// ---------------- ACT accumulate (R1) ----------------
__global__ __launch_bounds__(256) void k_acc(float* __restrict__ ws) {
  int i4 = blockIdx.x * 256 + threadIdx.x;
  int b = i4 >> 14;
  float wt = ws[OFF_WT + b];
  float4 z = ((const float4*)(ws + OFF_ZR))[i4];
  float4 a = ((float4*)(ws + OFF_AR))[i4];
  a.x += wt * z.x; a.y += wt * z.y; a.z += wt * z.z; a.w += wt * z.w;
  ((float4*)(ws + OFF_AR))[i4] = a;
  z = ((const float4*)(ws + OFF_ZI))[i4];
  a = ((float4*)(ws + OFF_AI))[i4];
  a.x += wt * z.x; a.y += wt * z.y; a.z += wt * z.z; a.w += wt * z.w;
  ((float4*)(ws + OFF_AI))[i4] = a;
}

// ---------------- output (R1) ----------------
__global__ __launch_bounds__(256) void k_out(const float* __restrict__ ws,
                                             float* __restrict__ out) {
  int i4 = blockIdx.x * 256 + threadIdx.x;
  ((float4*)out)[i4] = ((const float4*)(ws + OFF_AR))[i4];
  ((float4*)out)[i4 + BSD / 4] = ((const float4*)(ws + OFF_AI))[i4];
}

extern "C" void kernel_launch(void* const* d_in, const int* in_sizes, int n_in,
                              void* d_out, int out_size, void* d_ws, size_t ws_size,
                              hipStream_t stream) {
  (void)in_sizes; (void)n_in; (void)out_size; (void)ws_size;
  const float* x_real  = (const float*)d_in[0];
  const float* x_imag  = (const float*)d_in[1];
  const float* Wq_r    = (const float*)d_in[2];
  const float* Wq_i    = (const float*)d_in[3];
  const float* Wk_r    = (const float*)d_in[4];
  const float* Wk_i    = (const float*)d_in[5];
  const float* Wv_r    = (const float*)d_in[6];
  const float* Wv_i    = (const float*)d_in[7];
  const float* mod_bias = (const float*)d_in[8];
  const float* ln_scale = (const float*)d_in[9];
  const float* ln_shift = (const float*)d_in[10];
  const float* w_sal   = (const float*)d_in[11];
  const float* gru_Wih = (const float*)d_in[12];
  const float* gru_Whh = (const float*)d_in[13];
  const float* gru_bih = (const float*)d_in[14];
  const float* gru_bhh = (const float*)d_in[15];
  const float* bias_W  = (const float*)d_in[16];
  const float* bias_b  = (const float*)d_in[17];
  const float* w_halt  = (const float*)d_in[18];
  const float* b_halt  = (const float*)d_in[19];
  float* ws = (float*)d_ws;
  float* out = (float*)d_out;

  k_wprep<<<dim3(8, 8, 24), 256, 0, stream>>>(Wq_r, Wq_i, Wk_r, Wk_i, Wv_r, Wv_i, ws);
  k_init<<<512, 256, 0, stream>>>(x_real, x_imag, ws);
  k_gwp<<<32, 256, 0, stream>>>(ws + OFF_ZR, ws + OFF_ZI, ws + OFF_GWP);
  for (int step = 0; step < DEPTH; ++step) {
    const float* hold = ws + ((step & 1) ? OFF_H1 : OFF_H0);
    float* hnew = ws + ((step & 1) ? OFF_H0 : OFF_H1);
    k_gru<<<dim3(8, 8), 256, 0, stream>>>(ws + OFF_GWP, hold, hnew,
                                          gru_Wih, gru_Whh, gru_bih, gru_bhh);
    k_qkv<<<dim3(4, 8, 24), 256, 0, stream>>>(ws);
    k_attn<<<32, 256, 0, stream>>>(ws);
    k_pv<<<dim3(4, 32), 256, 0, stream>>>(ws);
    k_modln<<<M * B * S, 64, 0, stream>>>(ws, mod_bias, ln_scale, ln_shift);
    k_feat<<<256, 256, 0, stream>>>(ws);
    k_wsel<<<1, 256, 0, stream>>>(ws, hnew, bias_W, bias_b, w_sal);
    k_bcast<<<512, 256, 0, stream>>>(ws);
    k_gwp<<<32, 256, 0, stream>>>(ws + OFF_ZR, ws + OFF_ZI, ws + OFF_GWP);
    k_halt<<<1, 256, 0, stream>>>(ws, w_halt, b_halt);
    k_acc<<<512, 256, 0, stream>>>(ws);
  }
  k_out<<<512, 256, 0, stream>>>(ws, out);
}